// Round 3
// baseline (1277.643 us; speedup 1.0000x reference)
//
#include <hip/hip_runtime.h>
#include <hip/hip_bf16.h>
#include <cstdint>
#include <cstddef>

#define N_NODES 65536
#define N_EDGES 1048576
#define N_GRAPHS 128
#define NPG 512
#define IN_DIM 64
#define HID 128
#define BN_EPS 1e-5f

// ---------------- CSR build ----------------
__global__ __launch_bounds__(256) void hist_kernel(const int* __restrict__ dst,
                                                   int* __restrict__ deg) {
  int e = blockIdx.x * 256 + threadIdx.x;
  if (e < N_EDGES) atomicAdd(&deg[dst[e]], 1);
}

__global__ __launch_bounds__(256) void dis_kernel(const int* __restrict__ deg,
                                                  float* __restrict__ dis) {
  int n = blockIdx.x * 256 + threadIdx.x;
  if (n < N_NODES) dis[n] = 1.0f / sqrtf((float)deg[n] + 1.0f);
}

// single block of 1024 threads; each thread scans 64 contiguous counters
__global__ __launch_bounds__(1024) void scan_kernel(const int* __restrict__ deg,
                                                    int* __restrict__ offsets,
                                                    int* __restrict__ cursor) {
  __shared__ int sums[1024];
  int t = threadIdx.x;
  int base = t * 64;
  const int4* dp = (const int4*)(deg + base);
  int s = 0;
#pragma unroll
  for (int i = 0; i < 16; i++) {
    int4 v = dp[i];
    s += v.x + v.y + v.z + v.w;
  }
  sums[t] = s;
  __syncthreads();
  for (int off = 1; off < 1024; off <<= 1) {
    int v = (t >= off) ? sums[t - off] : 0;
    __syncthreads();
    sums[t] += v;
    __syncthreads();
  }
  int run = (t == 0) ? 0 : sums[t - 1];
#pragma unroll
  for (int i = 0; i < 16; i++) {
    int4 v = dp[i];
    int idx = base + i * 4;
    offsets[idx] = run; cursor[idx] = run; run += v.x;
    offsets[idx + 1] = run; cursor[idx + 1] = run; run += v.y;
    offsets[idx + 2] = run; cursor[idx + 2] = run; run += v.z;
    offsets[idx + 3] = run; cursor[idx + 3] = run; run += v.w;
  }
  if (t == 1023) offsets[N_NODES] = run;
}

__global__ __launch_bounds__(256) void fill_kernel(const int* __restrict__ src,
                                                   const int* __restrict__ dst,
                                                   int* __restrict__ cursor,
                                                   int* __restrict__ csr) {
  int e = blockIdx.x * 256 + threadIdx.x;
  if (e < N_EDGES) {
    int d = dst[e];
    int slot = atomicAdd(&cursor[d], 1);
    csr[slot] = src[e];
  }
}

// ---------------- aggregation (gather over CSR) ----------------
__global__ __launch_bounds__(256) void agg64_kernel(const float* __restrict__ x,
                                                    const float* __restrict__ dis,
                                                    const int* __restrict__ offsets,
                                                    const int* __restrict__ csr,
                                                    float* __restrict__ z) {
  int node = blockIdx.x * 4 + (threadIdx.x >> 6);
  int lane = threadIdx.x & 63;
  float dn = dis[node];
  float acc = x[(size_t)node * 64 + lane] * dn * dn;
  int beg = offsets[node], end = offsets[node + 1];
  for (int k = beg; k < end; k++) {
    int s = csr[k];
    acc = fmaf(dn * dis[s], x[(size_t)s * 64 + lane], acc);
  }
  z[(size_t)node * 64 + lane] = acc;
}

__global__ __launch_bounds__(256) void agg128_kernel(const float* __restrict__ h,
                                                     const float* __restrict__ dis,
                                                     const int* __restrict__ offsets,
                                                     const int* __restrict__ csr,
                                                     float* __restrict__ z) {
  int node = blockIdx.x * 4 + (threadIdx.x >> 6);
  int lane = threadIdx.x & 63;
  float dn = dis[node];
  float sn = dn * dn;
  const float* hr = h + (size_t)node * 128;
  float a0 = hr[lane] * sn;
  float a1 = hr[lane + 64] * sn;
  int beg = offsets[node], end = offsets[node + 1];
  for (int k = beg; k < end; k++) {
    int s = csr[k];
    float w = dn * dis[s];
    const float* hs = h + (size_t)s * 128;
    a0 = fmaf(w, hs[lane], a0);
    a1 = fmaf(w, hs[lane + 64], a1);
  }
  z[(size_t)node * 128 + lane] = a0;
  z[(size_t)node * 128 + lane + 64] = a1;
}

// ---------------- fused fp32 GEMM: C = A[N,K] * B (+bias, +BN, +ReLU) ----------------
template <int K, int O, bool BTRANS, bool DOBN, bool DORELU>
__global__ __launch_bounds__(256) void gemm_fused(const float* __restrict__ A,
                                                  const float* __restrict__ B,
                                                  const float* __restrict__ bias,
                                                  const float* __restrict__ gamma,
                                                  const float* __restrict__ beta,
                                                  const float* __restrict__ mean,
                                                  const float* __restrict__ var,
                                                  float* __restrict__ C) {
  constexpr int BM = 64, BO = 128, BK = 16;
  __shared__ float As[BK][BM + 4];
  __shared__ float Bs[BK][BO + 4];
  int tid = threadIdx.x;
  int m0 = blockIdx.x * BM;
  int o0 = blockIdx.y * BO;
  int tm = tid >> 4;
  int to = tid & 15;

  float acc[4][8];
#pragma unroll
  for (int i = 0; i < 4; i++)
#pragma unroll
    for (int j = 0; j < 8; j++) acc[i][j] = 0.0f;

  int arow = tid >> 2, aseg = tid & 3;

  for (int k0 = 0; k0 < K; k0 += BK) {
    float4 a4 = *(const float4*)&A[(size_t)(m0 + arow) * K + k0 + aseg * 4];
    float4 b0, b1;
    int bo = 0, bkh = 0;
    if (BTRANS) {
      bo = tid & 127;
      bkh = (tid >> 7) * 8;
      const float* bp = &B[(size_t)(o0 + bo) * K + k0 + bkh];
      b0 = *(const float4*)bp;
      b1 = *(const float4*)(bp + 4);
    } else {
      bkh = tid >> 4;
      bo = (tid & 15) * 8;
      const float* bp = &B[(size_t)(k0 + bkh) * O + o0 + bo];
      b0 = *(const float4*)bp;
      b1 = *(const float4*)(bp + 4);
    }
    __syncthreads();
    As[aseg * 4 + 0][arow] = a4.x;
    As[aseg * 4 + 1][arow] = a4.y;
    As[aseg * 4 + 2][arow] = a4.z;
    As[aseg * 4 + 3][arow] = a4.w;
    if (BTRANS) {
      Bs[bkh + 0][bo] = b0.x; Bs[bkh + 1][bo] = b0.y;
      Bs[bkh + 2][bo] = b0.z; Bs[bkh + 3][bo] = b0.w;
      Bs[bkh + 4][bo] = b1.x; Bs[bkh + 5][bo] = b1.y;
      Bs[bkh + 6][bo] = b1.z; Bs[bkh + 7][bo] = b1.w;
    } else {
      *(float4*)&Bs[bkh][bo] = b0;
      *(float4*)&Bs[bkh][bo + 4] = b1;
    }
    __syncthreads();
#pragma unroll
    for (int k = 0; k < BK; k++) {
      float4 av = *(const float4*)&As[k][tm * 4];
      float4 bv0 = *(const float4*)&Bs[k][to * 8];
      float4 bv1 = *(const float4*)&Bs[k][to * 8 + 4];
      float am[4] = {av.x, av.y, av.z, av.w};
      float bm[8] = {bv0.x, bv0.y, bv0.z, bv0.w, bv1.x, bv1.y, bv1.z, bv1.w};
#pragma unroll
      for (int i = 0; i < 4; i++)
#pragma unroll
        for (int j = 0; j < 8; j++) acc[i][j] = fmaf(am[i], bm[j], acc[i][j]);
    }
  }

  float cs[8], cb[8];
#pragma unroll
  for (int j = 0; j < 8; j++) {
    int c = o0 + to * 8 + j;
    float b = bias[c];
    if (DOBN) {
      float sc = gamma[c] * rsqrtf(var[c] + BN_EPS);
      cs[j] = sc;
      cb[j] = (b - mean[c]) * sc + beta[c];
    } else {
      cs[j] = 1.0f;
      cb[j] = b;
    }
  }
#pragma unroll
  for (int i = 0; i < 4; i++) {
    int row = m0 + tm * 4 + i;
    float out[8];
#pragma unroll
    for (int j = 0; j < 8; j++) {
      float v = fmaf(acc[i][j], cs[j], cb[j]);
      out[j] = DORELU ? fmaxf(v, 0.0f) : v;
    }
    float4* cp = (float4*)&C[(size_t)row * O + o0 + to * 8];
    cp[0] = make_float4(out[0], out[1], out[2], out[3]);
    cp[1] = make_float4(out[4], out[5], out[6], out[7]);
  }
}

// ---------------- key-norm max per (graph, head): bound for softmax shift ----------------
__global__ __launch_bounds__(256) void knorm_kernel(const float* __restrict__ qkv,
                                                    float* __restrict__ kmax2) {
  int g = blockIdx.x >> 2;
  int h = blockIdx.x & 3;
  size_t gbase = (size_t)g * NPG;
  float best = 0.0f;
#pragma unroll
  for (int r = 0; r < 2; r++) {
    int j = r * 256 + threadIdx.x;
    const float* kp = &qkv[(gbase + j) * 384 + 128 + h * 32];
    float s = 0.0f;
#pragma unroll
    for (int i = 0; i < 8; i++) {
      float4 v = *(const float4*)(kp + i * 4);
      s = fmaf(v.x, v.x, s);
      s = fmaf(v.y, v.y, s);
      s = fmaf(v.z, v.z, s);
      s = fmaf(v.w, v.w, s);
    }
    best = fmaxf(best, s);
  }
#pragma unroll
  for (int off = 32; off >= 1; off >>= 1)
    best = fmaxf(best, __shfl_xor(best, off, 64));
  __shared__ float red[4];
  int wave = threadIdx.x >> 6;
  if ((threadIdx.x & 63) == 0) red[wave] = best;
  __syncthreads();
  if (threadIdx.x == 0) {
    float m = fmaxf(fmaxf(red[0], red[1]), fmaxf(red[2], red[3]));
    kmax2[blockIdx.x] = m;
  }
}

// ---------------- attention: 2 queries/thread, single pass, double-buffered staging -----
// grid: 128 graphs x 4 heads = 512 blocks, 256 threads; thread owns queries t, t+256
__global__ __launch_bounds__(256, 2) void attn_kernel(const float* __restrict__ qkv,
                                                      const float* __restrict__ kmax2,
                                                      float* __restrict__ obuf) {
  int g = blockIdx.x >> 2;
  int h = blockIdx.x & 3;
  int t = threadIdx.x;
  const float scale = 0.17677669529663687f;  // 1/sqrt(32)
  size_t gbase = (size_t)g * NPG;

  __shared__ float sk[2][128][36];  // pad 36: staging writes conflict-light; reads broadcast
  __shared__ float sv[2][128][36];

  // load both queries, pre-scaled by 1/sqrt(dh)
  float q1[32], q2[32];
  float qn1 = 0.0f, qn2 = 0.0f;
  {
    const float* qp1 = &qkv[(gbase + t) * 384 + h * 32];
    const float* qp2 = &qkv[(gbase + t + 256) * 384 + h * 32];
#pragma unroll
    for (int i = 0; i < 8; i++) {
      float4 v1 = *(const float4*)(qp1 + i * 4);
      float4 v2 = *(const float4*)(qp2 + i * 4);
      q1[i * 4 + 0] = v1.x * scale; q1[i * 4 + 1] = v1.y * scale;
      q1[i * 4 + 2] = v1.z * scale; q1[i * 4 + 3] = v1.w * scale;
      q2[i * 4 + 0] = v2.x * scale; q2[i * 4 + 1] = v2.y * scale;
      q2[i * 4 + 2] = v2.z * scale; q2[i * 4 + 3] = v2.w * scale;
    }
#pragma unroll
    for (int d = 0; d < 32; d++) {
      qn1 = fmaf(q1[d], q1[d], qn1);
      qn2 = fmaf(q2[d], q2[d], qn2);
    }
  }
  // M >= max_j (q . k_j) by Cauchy-Schwarz; softmax shift-invariant for any M >= max
  float km2 = kmax2[g * 4 + h];
  float M1 = sqrtf(qn1 * km2);
  float M2 = sqrtf(qn2 * km2);

  int sr = t & 127;   // staged row within chunk
  int kvsel = t >> 7; // 0 -> stage k, 1 -> stage v

  // prefetch chunk 0 into registers, write to buffer 0
  float4 pre[8];
  {
    const float* gp = &qkv[(gbase + sr) * 384 + 128 + kvsel * 128 + h * 32];
#pragma unroll
    for (int i = 0; i < 8; i++) pre[i] = *(const float4*)(gp + i * 4);
    float* sp = kvsel ? &sv[0][sr][0] : &sk[0][sr][0];
#pragma unroll
    for (int i = 0; i < 8; i++) *(float4*)(sp + i * 4) = pre[i];
  }

  float o1[32], o2[32];
#pragma unroll
  for (int d = 0; d < 32; d++) { o1[d] = 0.0f; o2[d] = 0.0f; }
  float l1 = 0.0f, l2 = 0.0f;

  for (int c = 0; c < 4; c++) {
    __syncthreads();
    int cur = c & 1;
    // prefetch next chunk into registers (overlaps with compute below)
    if (c < 3) {
      const float* gp = &qkv[(gbase + (c + 1) * 128 + sr) * 384 + 128 + kvsel * 128 + h * 32];
#pragma unroll
      for (int i = 0; i < 8; i++) pre[i] = *(const float4*)(gp + i * 4);
    }
    const float(*skc)[36] = sk[cur];
    const float(*svc)[36] = sv[cur];
#pragma unroll 2
    for (int j = 0; j < 128; j++) {
      float s1 = 0.0f, s2 = 0.0f;
#pragma unroll
      for (int i = 0; i < 8; i++) {
        float4 kvv = *(const float4*)&skc[j][i * 4];
        s1 = fmaf(q1[i * 4 + 0], kvv.x, s1);
        s1 = fmaf(q1[i * 4 + 1], kvv.y, s1);
        s1 = fmaf(q1[i * 4 + 2], kvv.z, s1);
        s1 = fmaf(q1[i * 4 + 3], kvv.w, s1);
        s2 = fmaf(q2[i * 4 + 0], kvv.x, s2);
        s2 = fmaf(q2[i * 4 + 1], kvv.y, s2);
        s2 = fmaf(q2[i * 4 + 2], kvv.z, s2);
        s2 = fmaf(q2[i * 4 + 3], kvv.w, s2);
      }
      float p1 = __expf(s1 - M1);
      float p2 = __expf(s2 - M2);
      l1 += p1;
      l2 += p2;
#pragma unroll
      for (int i = 0; i < 8; i++) {
        float4 vv = *(const float4*)&svc[j][i * 4];
        o1[i * 4 + 0] = fmaf(p1, vv.x, o1[i * 4 + 0]);
        o1[i * 4 + 1] = fmaf(p1, vv.y, o1[i * 4 + 1]);
        o1[i * 4 + 2] = fmaf(p1, vv.z, o1[i * 4 + 2]);
        o1[i * 4 + 3] = fmaf(p1, vv.w, o1[i * 4 + 3]);
        o2[i * 4 + 0] = fmaf(p2, vv.x, o2[i * 4 + 0]);
        o2[i * 4 + 1] = fmaf(p2, vv.y, o2[i * 4 + 1]);
        o2[i * 4 + 2] = fmaf(p2, vv.z, o2[i * 4 + 2]);
        o2[i * 4 + 3] = fmaf(p2, vv.w, o2[i * 4 + 3]);
      }
    }
    // write prefetched chunk into the other buffer (readers of it are past the
    // barrier at loop top; it becomes visible after the next barrier)
    if (c < 3) {
      float* sp = kvsel ? &sv[cur ^ 1][sr][0] : &sk[cur ^ 1][sr][0];
#pragma unroll
      for (int i = 0; i < 8; i++) *(float4*)(sp + i * 4) = pre[i];
    }
  }

  float inv1 = 1.0f / l1;
  float inv2 = 1.0f / l2;
  float* op1 = &obuf[(gbase + t) * 128 + h * 32];
  float* op2 = &obuf[(gbase + t + 256) * 128 + h * 32];
#pragma unroll
  for (int i = 0; i < 8; i++) {
    *(float4*)(op1 + i * 4) = make_float4(o1[i * 4 + 0] * inv1, o1[i * 4 + 1] * inv1,
                                          o1[i * 4 + 2] * inv1, o1[i * 4 + 3] * inv1);
    *(float4*)(op2 + i * 4) = make_float4(o2[i * 4 + 0] * inv2, o2[i * 4 + 1] * inv2,
                                          o2[i * 4 + 2] * inv2, o2[i * 4 + 3] * inv2);
  }
}

// ---------------- mean pool ----------------
__global__ __launch_bounds__(128) void pool_kernel(const float* __restrict__ fin,
                                                   float* __restrict__ emb) {
  int g = blockIdx.x, c = threadIdx.x;
  const float* p = fin + (size_t)g * NPG * HID + c;
  float s = 0.0f;
  for (int i = 0; i < NPG; i++) s += p[(size_t)i * HID];
  emb[g * HID + c] = s * (1.0f / NPG);
}

extern "C" void kernel_launch(void* const* d_in, const int* in_sizes, int n_in,
                              void* d_out, int out_size, void* d_ws, size_t ws_size,
                              hipStream_t stream) {
  (void)in_sizes; (void)n_in; (void)out_size; (void)ws_size;
  const float* x          = (const float*)d_in[0];
  const float* W0         = (const float*)d_in[1];
  const float* b0         = (const float*)d_in[2];
  const float* Wh         = (const float*)d_in[3];
  const float* bh         = (const float*)d_in[4];
  const float* bn_gamma   = (const float*)d_in[5];
  const float* bn_beta    = (const float*)d_in[6];
  const float* bn_mean    = (const float*)d_in[7];
  const float* bn_var     = (const float*)d_in[8];
  const float* attn_in_w  = (const float*)d_in[9];
  const float* attn_in_b  = (const float*)d_in[10];
  const float* attn_out_w = (const float*)d_in[11];
  const float* attn_out_b = (const float*)d_in[12];
  const int* edge_index   = (const int*)d_in[13];
  const int* src = edge_index;
  const int* dst = edge_index + N_EDGES;

  char* ws = (char*)d_ws;
  size_t off = 0;
  auto alloc = [&](size_t bytes) -> void* {
    void* p = ws + off;
    off += (bytes + 255) & ~(size_t)255;
    return p;
  };
  int*   deg     = (int*)alloc((size_t)N_NODES * 4);
  int*   offsets = (int*)alloc((size_t)(N_NODES + 1) * 4);
  int*   cursor  = (int*)alloc((size_t)N_NODES * 4);
  int*   csr     = (int*)alloc((size_t)N_EDGES * 4);
  float* dis     = (float*)alloc((size_t)N_NODES * 4);
  float* bufA    = (float*)alloc((size_t)N_NODES * HID * 4);
  float* bufB    = (float*)alloc((size_t)N_NODES * HID * 4);
  float* qkvb    = (float*)alloc((size_t)N_NODES * 384 * 4);
  float* kmax2   = (float*)alloc((size_t)N_GRAPHS * 4 * 4);

  float* fin = (float*)d_out;                       // [N, HID]
  float* emb = fin + (size_t)N_NODES * HID;         // [G, HID]

  hipMemsetAsync(deg, 0, (size_t)N_NODES * 4, stream);
  hist_kernel<<<N_EDGES / 256, 256, 0, stream>>>(dst, deg);
  dis_kernel<<<N_NODES / 256, 256, 0, stream>>>(deg, dis);
  scan_kernel<<<1, 1024, 0, stream>>>(deg, offsets, cursor);
  fill_kernel<<<N_EDGES / 256, 256, 0, stream>>>(src, dst, cursor, csr);

  dim3 gemm_grid(N_NODES / 64, 1);
  agg64_kernel<<<N_NODES / 4, 256, 0, stream>>>(x, dis, offsets, csr, bufB);
  gemm_fused<64, 128, false, true, true><<<gemm_grid, 256, 0, stream>>>(
      bufB, W0, b0, bn_gamma, bn_beta, bn_mean, bn_var, bufA);
  for (int L = 0; L < 3; L++) {
    agg128_kernel<<<N_NODES / 4, 256, 0, stream>>>(bufA, dis, offsets, csr, bufB);
    gemm_fused<128, 128, false, true, true><<<gemm_grid, 256, 0, stream>>>(
        bufB, Wh + (size_t)L * HID * HID, bh + (size_t)L * HID,
        bn_gamma + (size_t)(L + 1) * HID, bn_beta + (size_t)(L + 1) * HID,
        bn_mean + (size_t)(L + 1) * HID, bn_var + (size_t)(L + 1) * HID, bufA);
  }
  dim3 qkv_grid(N_NODES / 64, 3);
  gemm_fused<128, 384, true, false, false><<<qkv_grid, 256, 0, stream>>>(
      bufA, attn_in_w, attn_in_b, nullptr, nullptr, nullptr, nullptr, qkvb);
  knorm_kernel<<<N_GRAPHS * 4, 256, 0, stream>>>(qkvb, kmax2);
  attn_kernel<<<N_GRAPHS * 4, 256, 0, stream>>>(qkvb, kmax2, bufB);
  gemm_fused<128, 128, true, false, false><<<gemm_grid, 256, 0, stream>>>(
      bufB, attn_out_w, attn_out_b, nullptr, nullptr, nullptr, nullptr, fin);
  pool_kernel<<<N_GRAPHS, 128, 0, stream>>>(fin, emb);
}

// Round 4
// 1208.661 us; speedup vs baseline: 1.0571x; 1.0571x over previous
//
#include <hip/hip_runtime.h>
#include <hip/hip_bf16.h>
#include <cstdint>
#include <cstddef>

#define N_NODES 65536
#define N_EDGES 1048576
#define N_GRAPHS 128
#define NPG 512
#define IN_DIM 64
#define HID 128
#define BN_EPS 1e-5f

// ---------------- CSR build ----------------
__global__ __launch_bounds__(256) void hist_kernel(const int* __restrict__ dst,
                                                   int* __restrict__ deg) {
  int e = blockIdx.x * 256 + threadIdx.x;
  if (e < N_EDGES) atomicAdd(&deg[dst[e]], 1);
}

__global__ __launch_bounds__(256) void dis_kernel(const int* __restrict__ deg,
                                                  float* __restrict__ dis) {
  int n = blockIdx.x * 256 + threadIdx.x;
  if (n < N_NODES) dis[n] = 1.0f / sqrtf((float)deg[n] + 1.0f);
}

// single block of 1024 threads; each thread scans 64 contiguous counters
__global__ __launch_bounds__(1024) void scan_kernel(const int* __restrict__ deg,
                                                    int* __restrict__ offsets,
                                                    int* __restrict__ cursor) {
  __shared__ int sums[1024];
  int t = threadIdx.x;
  int base = t * 64;
  const int4* dp = (const int4*)(deg + base);
  int s = 0;
#pragma unroll
  for (int i = 0; i < 16; i++) {
    int4 v = dp[i];
    s += v.x + v.y + v.z + v.w;
  }
  sums[t] = s;
  __syncthreads();
  for (int off = 1; off < 1024; off <<= 1) {
    int v = (t >= off) ? sums[t - off] : 0;
    __syncthreads();
    sums[t] += v;
    __syncthreads();
  }
  int run = (t == 0) ? 0 : sums[t - 1];
#pragma unroll
  for (int i = 0; i < 16; i++) {
    int4 v = dp[i];
    int idx = base + i * 4;
    offsets[idx] = run; cursor[idx] = run; run += v.x;
    offsets[idx + 1] = run; cursor[idx + 1] = run; run += v.y;
    offsets[idx + 2] = run; cursor[idx + 2] = run; run += v.z;
    offsets[idx + 3] = run; cursor[idx + 3] = run; run += v.w;
  }
  if (t == 1023) offsets[N_NODES] = run;
}

__global__ __launch_bounds__(256) void fill_kernel(const int* __restrict__ src,
                                                   const int* __restrict__ dst,
                                                   int* __restrict__ cursor,
                                                   int* __restrict__ csr) {
  int e = blockIdx.x * 256 + threadIdx.x;
  if (e < N_EDGES) {
    int d = dst[e];
    int slot = atomicAdd(&cursor[d], 1);
    csr[slot] = src[e];
  }
}

// ---------------- aggregation (gather over CSR) ----------------
__global__ __launch_bounds__(256) void agg64_kernel(const float* __restrict__ x,
                                                    const float* __restrict__ dis,
                                                    const int* __restrict__ offsets,
                                                    const int* __restrict__ csr,
                                                    float* __restrict__ z) {
  int node = blockIdx.x * 4 + (threadIdx.x >> 6);
  int lane = threadIdx.x & 63;
  float dn = dis[node];
  float acc = x[(size_t)node * 64 + lane] * dn * dn;
  int beg = offsets[node], end = offsets[node + 1];
  for (int k = beg; k < end; k++) {
    int s = csr[k];
    acc = fmaf(dn * dis[s], x[(size_t)s * 64 + lane], acc);
  }
  z[(size_t)node * 64 + lane] = acc;
}

__global__ __launch_bounds__(256) void agg128_kernel(const float* __restrict__ h,
                                                     const float* __restrict__ dis,
                                                     const int* __restrict__ offsets,
                                                     const int* __restrict__ csr,
                                                     float* __restrict__ z) {
  int node = blockIdx.x * 4 + (threadIdx.x >> 6);
  int lane = threadIdx.x & 63;
  float dn = dis[node];
  float sn = dn * dn;
  const float* hr = h + (size_t)node * 128;
  float a0 = hr[lane] * sn;
  float a1 = hr[lane + 64] * sn;
  int beg = offsets[node], end = offsets[node + 1];
  for (int k = beg; k < end; k++) {
    int s = csr[k];
    float w = dn * dis[s];
    const float* hs = h + (size_t)s * 128;
    a0 = fmaf(w, hs[lane], a0);
    a1 = fmaf(w, hs[lane + 64], a1);
  }
  z[(size_t)node * 128 + lane] = a0;
  z[(size_t)node * 128 + lane + 64] = a1;
}

// ---------------- fused fp32 GEMM: C = A[N,K] * B (+bias, +BN, +ReLU) ----------------
template <int K, int O, bool BTRANS, bool DOBN, bool DORELU>
__global__ __launch_bounds__(256) void gemm_fused(const float* __restrict__ A,
                                                  const float* __restrict__ B,
                                                  const float* __restrict__ bias,
                                                  const float* __restrict__ gamma,
                                                  const float* __restrict__ beta,
                                                  const float* __restrict__ mean,
                                                  const float* __restrict__ var,
                                                  float* __restrict__ C) {
  constexpr int BM = 64, BO = 128, BK = 16;
  __shared__ float As[BK][BM + 4];
  __shared__ float Bs[BK][BO + 4];
  int tid = threadIdx.x;
  int m0 = blockIdx.x * BM;
  int o0 = blockIdx.y * BO;
  int tm = tid >> 4;
  int to = tid & 15;

  float acc[4][8];
#pragma unroll
  for (int i = 0; i < 4; i++)
#pragma unroll
    for (int j = 0; j < 8; j++) acc[i][j] = 0.0f;

  int arow = tid >> 2, aseg = tid & 3;

  for (int k0 = 0; k0 < K; k0 += BK) {
    float4 a4 = *(const float4*)&A[(size_t)(m0 + arow) * K + k0 + aseg * 4];
    float4 b0, b1;
    int bo = 0, bkh = 0;
    if (BTRANS) {
      bo = tid & 127;
      bkh = (tid >> 7) * 8;
      const float* bp = &B[(size_t)(o0 + bo) * K + k0 + bkh];
      b0 = *(const float4*)bp;
      b1 = *(const float4*)(bp + 4);
    } else {
      bkh = tid >> 4;
      bo = (tid & 15) * 8;
      const float* bp = &B[(size_t)(k0 + bkh) * O + o0 + bo];
      b0 = *(const float4*)bp;
      b1 = *(const float4*)(bp + 4);
    }
    __syncthreads();
    As[aseg * 4 + 0][arow] = a4.x;
    As[aseg * 4 + 1][arow] = a4.y;
    As[aseg * 4 + 2][arow] = a4.z;
    As[aseg * 4 + 3][arow] = a4.w;
    if (BTRANS) {
      Bs[bkh + 0][bo] = b0.x; Bs[bkh + 1][bo] = b0.y;
      Bs[bkh + 2][bo] = b0.z; Bs[bkh + 3][bo] = b0.w;
      Bs[bkh + 4][bo] = b1.x; Bs[bkh + 5][bo] = b1.y;
      Bs[bkh + 6][bo] = b1.z; Bs[bkh + 7][bo] = b1.w;
    } else {
      *(float4*)&Bs[bkh][bo] = b0;
      *(float4*)&Bs[bkh][bo + 4] = b1;
    }
    __syncthreads();
#pragma unroll
    for (int k = 0; k < BK; k++) {
      float4 av = *(const float4*)&As[k][tm * 4];
      float4 bv0 = *(const float4*)&Bs[k][to * 8];
      float4 bv1 = *(const float4*)&Bs[k][to * 8 + 4];
      float am[4] = {av.x, av.y, av.z, av.w};
      float bm[8] = {bv0.x, bv0.y, bv0.z, bv0.w, bv1.x, bv1.y, bv1.z, bv1.w};
#pragma unroll
      for (int i = 0; i < 4; i++)
#pragma unroll
        for (int j = 0; j < 8; j++) acc[i][j] = fmaf(am[i], bm[j], acc[i][j]);
    }
  }

  float cs[8], cb[8];
#pragma unroll
  for (int j = 0; j < 8; j++) {
    int c = o0 + to * 8 + j;
    float b = bias[c];
    if (DOBN) {
      float sc = gamma[c] * rsqrtf(var[c] + BN_EPS);
      cs[j] = sc;
      cb[j] = (b - mean[c]) * sc + beta[c];
    } else {
      cs[j] = 1.0f;
      cb[j] = b;
    }
  }
#pragma unroll
  for (int i = 0; i < 4; i++) {
    int row = m0 + tm * 4 + i;
    float out[8];
#pragma unroll
    for (int j = 0; j < 8; j++) {
      float v = fmaf(acc[i][j], cs[j], cb[j]);
      out[j] = DORELU ? fmaxf(v, 0.0f) : v;
    }
    float4* cp = (float4*)&C[(size_t)row * O + o0 + to * 8];
    cp[0] = make_float4(out[0], out[1], out[2], out[3]);
    cp[1] = make_float4(out[4], out[5], out[6], out[7]);
  }
}

// ---------------- key-norm max per (graph, head): bound for softmax shift ----------------
__global__ __launch_bounds__(256) void knorm_kernel(const float* __restrict__ qkv,
                                                    float* __restrict__ kmax2) {
  int g = blockIdx.x >> 2;
  int h = blockIdx.x & 3;
  size_t gbase = (size_t)g * NPG;
  float best = 0.0f;
#pragma unroll
  for (int r = 0; r < 2; r++) {
    int j = r * 256 + threadIdx.x;
    const float* kp = &qkv[(gbase + j) * 384 + 128 + h * 32];
    float s = 0.0f;
#pragma unroll
    for (int i = 0; i < 8; i++) {
      float4 v = *(const float4*)(kp + i * 4);
      s = fmaf(v.x, v.x, s);
      s = fmaf(v.y, v.y, s);
      s = fmaf(v.z, v.z, s);
      s = fmaf(v.w, v.w, s);
    }
    best = fmaxf(best, s);
  }
#pragma unroll
  for (int off = 32; off >= 1; off >>= 1)
    best = fmaxf(best, __shfl_xor(best, off, 64));
  __shared__ float red[4];
  int wave = threadIdx.x >> 6;
  if ((threadIdx.x & 63) == 0) red[wave] = best;
  __syncthreads();
  if (threadIdx.x == 0) {
    float m = fmaxf(fmaxf(red[0], red[1]), fmaxf(red[2], red[3]));
    kmax2[blockIdx.x] = m;
  }
}

// ---------------- attention: lane-pair dim-split, single pass -------------------------
// grid: 128 g x 4 h = 512 blocks; block: 512 threads = 8 waves.
// Wave w owns queries [w*64, w*64+64). Lane i (i<32) pairs with lane i+32:
// pair p=i handles queries qA=w*64+p and qB=qA+32; lane i holds dims [0:16),
// lane i+32 holds dims [16:32). Score halves combined via __shfl_xor(·,32).
// Per-lane state: 2x16 q + 2x16 o = 64 VGPRs -> no spill at 4 waves/EU.
__global__ __launch_bounds__(512, 4) void attn_kernel(const float* __restrict__ qkv,
                                                      const float* __restrict__ kmax2,
                                                      float* __restrict__ obuf) {
  int g = blockIdx.x >> 2;
  int h = blockIdx.x & 3;
  int t = threadIdx.x;
  int wave = t >> 6;
  int lane = t & 63;
  int pr = lane & 31;
  int hi = lane >> 5;  // 0: dims [0:16), 1: dims [16:32)
  size_t gbase = (size_t)g * NPG;

  // scale*log2(e): compute scores in log2 domain, exp2 is native v_exp_f32
  const float cf = 0.17677669529663687f * 1.4426950408889634f;

  __shared__ float sk[128][36];  // 36-float rows: halves land 16 banks apart
  __shared__ float sv[128][36];

  int qA = wave * 64 + pr;
  int qB = qA + 32;

  // load my dim-half of both queries, pre-scaled
  float a[16], b[16];
  {
    const float* pA = &qkv[(gbase + qA) * 384 + h * 32 + hi * 16];
    const float* pB = &qkv[(gbase + qB) * 384 + h * 32 + hi * 16];
#pragma unroll
    for (int i = 0; i < 4; i++) {
      float4 vA = *(const float4*)(pA + i * 4);
      float4 vB = *(const float4*)(pB + i * 4);
      a[i * 4 + 0] = vA.x * cf; a[i * 4 + 1] = vA.y * cf;
      a[i * 4 + 2] = vA.z * cf; a[i * 4 + 3] = vA.w * cf;
      b[i * 4 + 0] = vB.x * cf; b[i * 4 + 1] = vB.y * cf;
      b[i * 4 + 2] = vB.z * cf; b[i * 4 + 3] = vB.w * cf;
    }
  }
  // full |q_scaled|^2 via half-sum + partner half
  float na = 0.0f, nb = 0.0f;
#pragma unroll
  for (int d = 0; d < 16; d++) {
    na = fmaf(a[d], a[d], na);
    nb = fmaf(b[d], b[d], nb);
  }
  na += __shfl_xor(na, 32);
  nb += __shfl_xor(nb, 32);
  float km2 = kmax2[g * 4 + h];
  // Cauchy-Schwarz bound in log2 domain; softmax shift-invariant for any M >= max
  float MA = sqrtf(na * km2);
  float MB = sqrtf(nb * km2);

  float oA[16], oB[16];
#pragma unroll
  for (int d = 0; d < 16; d++) { oA[d] = 0.0f; oB[d] = 0.0f; }
  float lA = 0.0f, lB = 0.0f;

  // staging roles: 512 threads cover 128 rows x {k-lo, k-hi, v-lo, v-hi}
  int srow = t & 127;
  int ssel = t >> 7;       // 0..3
  int iskv = ssel >> 1;    // 0=k, 1=v (wave-uniform)
  int seg = ssel & 1;      // 16-float segment

  for (int c = 0; c < 4; c++) {
    __syncthreads();
    {
      const float* gp = &qkv[(gbase + (size_t)(c * 128 + srow)) * 384 + 128 +
                             iskv * 128 + h * 32 + seg * 16];
      float* sp = iskv ? &sv[srow][seg * 16] : &sk[srow][seg * 16];
#pragma unroll
      for (int i = 0; i < 4; i++) *(float4*)(sp + i * 4) = *(const float4*)(gp + i * 4);
    }
    __syncthreads();
#pragma unroll 2
    for (int j = 0; j < 128; j++) {
      const float* kp = &sk[j][hi * 16];
      float4 k0 = *(const float4*)(kp);
      float4 k1 = *(const float4*)(kp + 4);
      float4 k2 = *(const float4*)(kp + 8);
      float4 k3 = *(const float4*)(kp + 12);
      // 4 independent partial chains per query -> short dep chains
      float sa0 = fmaf(a[3], k0.w, fmaf(a[2], k0.z, fmaf(a[1], k0.y, a[0] * k0.x)));
      float sa1 = fmaf(a[7], k1.w, fmaf(a[6], k1.z, fmaf(a[5], k1.y, a[4] * k1.x)));
      float sa2 = fmaf(a[11], k2.w, fmaf(a[10], k2.z, fmaf(a[9], k2.y, a[8] * k2.x)));
      float sa3 = fmaf(a[15], k3.w, fmaf(a[14], k3.z, fmaf(a[13], k3.y, a[12] * k3.x)));
      float sb0 = fmaf(b[3], k0.w, fmaf(b[2], k0.z, fmaf(b[1], k0.y, b[0] * k0.x)));
      float sb1 = fmaf(b[7], k1.w, fmaf(b[6], k1.z, fmaf(b[5], k1.y, b[4] * k1.x)));
      float sb2 = fmaf(b[11], k2.w, fmaf(b[10], k2.z, fmaf(b[9], k2.y, b[8] * k2.x)));
      float sb3 = fmaf(b[15], k3.w, fmaf(b[14], k3.z, fmaf(b[13], k3.y, b[12] * k3.x)));
      float sa = (sa0 + sa1) + (sa2 + sa3);
      float sb = (sb0 + sb1) + (sb2 + sb3);
      sa += __shfl_xor(sa, 32);  // add partner's dim-half (identical on both lanes)
      sb += __shfl_xor(sb, 32);
      float pa = __builtin_exp2f(sa - MA);
      float pb = __builtin_exp2f(sb - MB);
      lA += pa;
      lB += pb;
      const float* vp = &sv[j][hi * 16];
      float4 v0 = *(const float4*)(vp);
      float4 v1 = *(const float4*)(vp + 4);
      float4 v2 = *(const float4*)(vp + 8);
      float4 v3 = *(const float4*)(vp + 12);
      oA[0] = fmaf(pa, v0.x, oA[0]);   oA[1] = fmaf(pa, v0.y, oA[1]);
      oA[2] = fmaf(pa, v0.z, oA[2]);   oA[3] = fmaf(pa, v0.w, oA[3]);
      oA[4] = fmaf(pa, v1.x, oA[4]);   oA[5] = fmaf(pa, v1.y, oA[5]);
      oA[6] = fmaf(pa, v1.z, oA[6]);   oA[7] = fmaf(pa, v1.w, oA[7]);
      oA[8] = fmaf(pa, v2.x, oA[8]);   oA[9] = fmaf(pa, v2.y, oA[9]);
      oA[10] = fmaf(pa, v2.z, oA[10]); oA[11] = fmaf(pa, v2.w, oA[11]);
      oA[12] = fmaf(pa, v3.x, oA[12]); oA[13] = fmaf(pa, v3.y, oA[13]);
      oA[14] = fmaf(pa, v3.z, oA[14]); oA[15] = fmaf(pa, v3.w, oA[15]);
      oB[0] = fmaf(pb, v0.x, oB[0]);   oB[1] = fmaf(pb, v0.y, oB[1]);
      oB[2] = fmaf(pb, v0.z, oB[2]);   oB[3] = fmaf(pb, v0.w, oB[3]);
      oB[4] = fmaf(pb, v1.x, oB[4]);   oB[5] = fmaf(pb, v1.y, oB[5]);
      oB[6] = fmaf(pb, v1.z, oB[6]);   oB[7] = fmaf(pb, v1.w, oB[7]);
      oB[8] = fmaf(pb, v2.x, oB[8]);   oB[9] = fmaf(pb, v2.y, oB[9]);
      oB[10] = fmaf(pb, v2.z, oB[10]); oB[11] = fmaf(pb, v2.w, oB[11]);
      oB[12] = fmaf(pb, v3.x, oB[12]); oB[13] = fmaf(pb, v3.y, oB[13]);
      oB[14] = fmaf(pb, v3.z, oB[14]); oB[15] = fmaf(pb, v3.w, oB[15]);
    }
  }

  float iA = 1.0f / lA;
  float iB = 1.0f / lB;
  float* oPA = &obuf[(gbase + qA) * 128 + h * 32 + hi * 16];
  float* oPB = &obuf[(gbase + qB) * 128 + h * 32 + hi * 16];
#pragma unroll
  for (int i = 0; i < 4; i++) {
    *(float4*)(oPA + i * 4) = make_float4(oA[i * 4] * iA, oA[i * 4 + 1] * iA,
                                          oA[i * 4 + 2] * iA, oA[i * 4 + 3] * iA);
    *(float4*)(oPB + i * 4) = make_float4(oB[i * 4] * iB, oB[i * 4 + 1] * iB,
                                          oB[i * 4 + 2] * iB, oB[i * 4 + 3] * iB);
  }
}

// ---------------- mean pool ----------------
__global__ __launch_bounds__(128) void pool_kernel(const float* __restrict__ fin,
                                                   float* __restrict__ emb) {
  int g = blockIdx.x, c = threadIdx.x;
  const float* p = fin + (size_t)g * NPG * HID + c;
  float s = 0.0f;
  for (int i = 0; i < NPG; i++) s += p[(size_t)i * HID];
  emb[g * HID + c] = s * (1.0f / NPG);
}

extern "C" void kernel_launch(void* const* d_in, const int* in_sizes, int n_in,
                              void* d_out, int out_size, void* d_ws, size_t ws_size,
                              hipStream_t stream) {
  (void)in_sizes; (void)n_in; (void)out_size; (void)ws_size;
  const float* x          = (const float*)d_in[0];
  const float* W0         = (const float*)d_in[1];
  const float* b0         = (const float*)d_in[2];
  const float* Wh         = (const float*)d_in[3];
  const float* bh         = (const float*)d_in[4];
  const float* bn_gamma   = (const float*)d_in[5];
  const float* bn_beta    = (const float*)d_in[6];
  const float* bn_mean    = (const float*)d_in[7];
  const float* bn_var     = (const float*)d_in[8];
  const float* attn_in_w  = (const float*)d_in[9];
  const float* attn_in_b  = (const float*)d_in[10];
  const float* attn_out_w = (const float*)d_in[11];
  const float* attn_out_b = (const float*)d_in[12];
  const int* edge_index   = (const int*)d_in[13];
  const int* src = edge_index;
  const int* dst = edge_index + N_EDGES;

  char* ws = (char*)d_ws;
  size_t off = 0;
  auto alloc = [&](size_t bytes) -> void* {
    void* p = ws + off;
    off += (bytes + 255) & ~(size_t)255;
    return p;
  };
  int*   deg     = (int*)alloc((size_t)N_NODES * 4);
  int*   offsets = (int*)alloc((size_t)(N_NODES + 1) * 4);
  int*   cursor  = (int*)alloc((size_t)N_NODES * 4);
  int*   csr     = (int*)alloc((size_t)N_EDGES * 4);
  float* dis     = (float*)alloc((size_t)N_NODES * 4);
  float* bufA    = (float*)alloc((size_t)N_NODES * HID * 4);
  float* bufB    = (float*)alloc((size_t)N_NODES * HID * 4);
  float* qkvb    = (float*)alloc((size_t)N_NODES * 384 * 4);
  float* kmax2   = (float*)alloc((size_t)N_GRAPHS * 4 * 4);

  float* fin = (float*)d_out;                       // [N, HID]
  float* emb = fin + (size_t)N_NODES * HID;         // [G, HID]

  hipMemsetAsync(deg, 0, (size_t)N_NODES * 4, stream);
  hist_kernel<<<N_EDGES / 256, 256, 0, stream>>>(dst, deg);
  dis_kernel<<<N_NODES / 256, 256, 0, stream>>>(deg, dis);
  scan_kernel<<<1, 1024, 0, stream>>>(deg, offsets, cursor);
  fill_kernel<<<N_EDGES / 256, 256, 0, stream>>>(src, dst, cursor, csr);

  dim3 gemm_grid(N_NODES / 64, 1);
  agg64_kernel<<<N_NODES / 4, 256, 0, stream>>>(x, dis, offsets, csr, bufB);
  gemm_fused<64, 128, false, true, true><<<gemm_grid, 256, 0, stream>>>(
      bufB, W0, b0, bn_gamma, bn_beta, bn_mean, bn_var, bufA);
  for (int L = 0; L < 3; L++) {
    agg128_kernel<<<N_NODES / 4, 256, 0, stream>>>(bufA, dis, offsets, csr, bufB);
    gemm_fused<128, 128, false, true, true><<<gemm_grid, 256, 0, stream>>>(
        bufB, Wh + (size_t)L * HID * HID, bh + (size_t)L * HID,
        bn_gamma + (size_t)(L + 1) * HID, bn_beta + (size_t)(L + 1) * HID,
        bn_mean + (size_t)(L + 1) * HID, bn_var + (size_t)(L + 1) * HID, bufA);
  }
  dim3 qkv_grid(N_NODES / 64, 3);
  gemm_fused<128, 384, true, false, false><<<qkv_grid, 256, 0, stream>>>(
      bufA, attn_in_w, attn_in_b, nullptr, nullptr, nullptr, nullptr, qkvb);
  knorm_kernel<<<N_GRAPHS * 4, 256, 0, stream>>>(qkvb, kmax2);
  attn_kernel<<<N_GRAPHS * 4, 512, 0, stream>>>(qkvb, kmax2, bufB);
  gemm_fused<128, 128, true, false, false><<<gemm_grid, 256, 0, stream>>>(
      bufB, attn_out_w, attn_out_b, nullptr, nullptr, nullptr, nullptr, fin);
  pool_kernel<<<N_GRAPHS, 128, 0, stream>>>(fin, emb);
}

// Round 5
// 1151.752 us; speedup vs baseline: 1.1093x; 1.0494x over previous
//
#include <hip/hip_runtime.h>
#include <hip/hip_bf16.h>
#include <cstdint>
#include <cstddef>

#define N_NODES 65536
#define N_EDGES 1048576
#define N_GRAPHS 128
#define NPG 512
#define IN_DIM 64
#define HID 128
#define BN_EPS 1e-5f

typedef __attribute__((ext_vector_type(8))) short bf16x8;
typedef __attribute__((ext_vector_type(4))) float f32x4;
typedef __attribute__((ext_vector_type(8))) unsigned short u16x8;

// ---- bf16 helpers (RNE, matches v_cvt) ----
__device__ inline unsigned short f2bf(float f) {
  unsigned u = __builtin_bit_cast(unsigned, f);
  u = u + 0x7fffu + ((u >> 16) & 1u);
  return (unsigned short)(u >> 16);
}
__device__ inline float bf2f(unsigned short h) {
  unsigned u = ((unsigned)h) << 16;
  return __builtin_bit_cast(float, u);
}
__device__ inline void split_bf(float v, unsigned short& hi, unsigned short& lo) {
  hi = f2bf(v);
  lo = f2bf(v - bf2f(hi));
}

// ---------------- CSR build ----------------
__global__ __launch_bounds__(256) void hist_kernel(const int* __restrict__ dst,
                                                   int* __restrict__ deg) {
  int e = blockIdx.x * 256 + threadIdx.x;
  if (e < N_EDGES) atomicAdd(&deg[dst[e]], 1);
}

__global__ __launch_bounds__(256) void dis_kernel(const int* __restrict__ deg,
                                                  float* __restrict__ dis) {
  int n = blockIdx.x * 256 + threadIdx.x;
  if (n < N_NODES) dis[n] = 1.0f / sqrtf((float)deg[n] + 1.0f);
}

__global__ __launch_bounds__(1024) void scan_kernel(const int* __restrict__ deg,
                                                    int* __restrict__ offsets,
                                                    int* __restrict__ cursor) {
  __shared__ int sums[1024];
  int t = threadIdx.x;
  int base = t * 64;
  const int4* dp = (const int4*)(deg + base);
  int s = 0;
#pragma unroll
  for (int i = 0; i < 16; i++) {
    int4 v = dp[i];
    s += v.x + v.y + v.z + v.w;
  }
  sums[t] = s;
  __syncthreads();
  for (int off = 1; off < 1024; off <<= 1) {
    int v = (t >= off) ? sums[t - off] : 0;
    __syncthreads();
    sums[t] += v;
    __syncthreads();
  }
  int run = (t == 0) ? 0 : sums[t - 1];
#pragma unroll
  for (int i = 0; i < 16; i++) {
    int4 v = dp[i];
    int idx = base + i * 4;
    offsets[idx] = run; cursor[idx] = run; run += v.x;
    offsets[idx + 1] = run; cursor[idx + 1] = run; run += v.y;
    offsets[idx + 2] = run; cursor[idx + 2] = run; run += v.z;
    offsets[idx + 3] = run; cursor[idx + 3] = run; run += v.w;
  }
  if (t == 1023) offsets[N_NODES] = run;
}

__global__ __launch_bounds__(256) void fill_kernel(const int* __restrict__ src,
                                                   const int* __restrict__ dst,
                                                   int* __restrict__ cursor,
                                                   int* __restrict__ csr) {
  int e = blockIdx.x * 256 + threadIdx.x;
  if (e < N_EDGES) {
    int d = dst[e];
    int slot = atomicAdd(&cursor[d], 1);
    csr[slot] = src[e];
  }
}

// ---------------- aggregation (gather over CSR), split-bf16 output ----------------
__global__ __launch_bounds__(256) void agg64_kernel(const float* __restrict__ x,
                                                    const float* __restrict__ dis,
                                                    const int* __restrict__ offsets,
                                                    const int* __restrict__ csr,
                                                    unsigned short* __restrict__ zhi,
                                                    unsigned short* __restrict__ zlo) {
  int node = blockIdx.x * 4 + (threadIdx.x >> 6);
  int lane = threadIdx.x & 63;
  float dn = dis[node];
  float acc = x[(size_t)node * 64 + lane] * dn * dn;
  int beg = offsets[node], end = offsets[node + 1];
  for (int k = beg; k < end; k++) {
    int s = csr[k];
    acc = fmaf(dn * dis[s], x[(size_t)s * 64 + lane], acc);
  }
  unsigned short h_, l_;
  split_bf(acc, h_, l_);
  zhi[(size_t)node * 64 + lane] = h_;
  zlo[(size_t)node * 64 + lane] = l_;
}

__global__ __launch_bounds__(256) void agg128_kernel(const float* __restrict__ h,
                                                     const float* __restrict__ dis,
                                                     const int* __restrict__ offsets,
                                                     const int* __restrict__ csr,
                                                     unsigned short* __restrict__ zhi,
                                                     unsigned short* __restrict__ zlo) {
  int node = blockIdx.x * 4 + (threadIdx.x >> 6);
  int lane = threadIdx.x & 63;
  float dn = dis[node];
  float sn = dn * dn;
  const float* hr = h + (size_t)node * 128;
  float a0 = hr[lane] * sn;
  float a1 = hr[lane + 64] * sn;
  int beg = offsets[node], end = offsets[node + 1];
  for (int k = beg; k < end; k++) {
    int s = csr[k];
    float w = dn * dis[s];
    const float* hs = h + (size_t)s * 128;
    a0 = fmaf(w, hs[lane], a0);
    a1 = fmaf(w, hs[lane + 64], a1);
  }
  unsigned short h0, l0, h1, l1;
  split_bf(a0, h0, l0);
  split_bf(a1, h1, l1);
  zhi[(size_t)node * 128 + lane] = h0;
  zlo[(size_t)node * 128 + lane] = l0;
  zhi[(size_t)node * 128 + lane + 64] = h1;
  zlo[(size_t)node * 128 + lane + 64] = l1;
}

// ---------------- weight prep: fp32 W -> bf16 hi/lo in b-fragment layout ----------------
// b-frag for 16x16x32: lane holds B[k0+(lane>>4)*8+j][n0+(lane&15)], j=0..7
// frag storage index: ((ntile*KC + kchunk)*64 + lane)*8 + j
template <bool TRANS>
__global__ __launch_bounds__(256) void wprep_kernel(const float* __restrict__ W, int K, int O,
                                                    unsigned short* __restrict__ hi,
                                                    unsigned short* __restrict__ lo) {
  int idx = blockIdx.x * 256 + threadIdx.x;
  int KC = K / 32;
  int total = (O / 16) * KC * 64;
  if (idx >= total) return;
  int lane = idx & 63;
  int rest = idx >> 6;
  int kc = rest % KC;
  int nt = rest / KC;
  int n = nt * 16 + (lane & 15);
  int kb = kc * 32 + (lane >> 4) * 8;
  unsigned short* hp = hi + (size_t)idx * 8;
  unsigned short* lp = lo + (size_t)idx * 8;
#pragma unroll
  for (int j = 0; j < 8; j++) {
    int k = kb + j;
    float v = TRANS ? W[(size_t)n * K + k] : W[(size_t)k * O + n];
    unsigned short h_, l_;
    split_bf(v, h_, l_);
    hp[j] = h_;
    lp[j] = l_;
  }
}

// ---------------- MFMA GEMM: C[N,O] = (Ahi+Alo)[N,K] x (Whi+Wlo) (+bias,BN,ReLU) -----
// block: 256 thr / 4 waves; wave w owns rows [blk*128 + w*32, +32), 128 cols.
// 4 split-products per tile: hh + hl + lh + ll  (~fp32 accuracy).
template <int K, int O, bool DOBN, bool DORELU, bool SPLIT_OUT>
__global__ __launch_bounds__(256) void gemm_mfma(
    const unsigned short* __restrict__ Ahi, const unsigned short* __restrict__ Alo,
    const unsigned short* __restrict__ Whi, const unsigned short* __restrict__ Wlo,
    const float* __restrict__ bias,
    const float* __restrict__ gamma, const float* __restrict__ beta,
    const float* __restrict__ mean, const float* __restrict__ var,
    float* __restrict__ Cf, unsigned short* __restrict__ Chi,
    unsigned short* __restrict__ Clo) {
  constexpr int KC = K / 32;
  int wave = threadIdx.x >> 6;
  int lane = threadIdx.x & 63;
  int m0 = blockIdx.x * 128 + wave * 32;
  int o0 = blockIdx.y * 128;
  int mrow = lane & 15;
  int kseg = (lane >> 4) * 8;

  f32x4 acc[2][8];
#pragma unroll
  for (int mt = 0; mt < 2; mt++)
#pragma unroll
    for (int nt = 0; nt < 8; nt++) acc[mt][nt] = (f32x4)0.0f;

#pragma unroll
  for (int kc = 0; kc < KC; kc++) {
    bf16x8 ah[2], al[2];
#pragma unroll
    for (int mt = 0; mt < 2; mt++) {
      size_t aoff = (size_t)(m0 + mt * 16 + mrow) * K + kc * 32 + kseg;
      ah[mt] = *(const bf16x8*)(Ahi + aoff);
      al[mt] = *(const bf16x8*)(Alo + aoff);
    }
#pragma unroll
    for (int nt = 0; nt < 8; nt++) {
      size_t foff = (((size_t)(blockIdx.y * 8 + nt) * KC + kc) * 64 + lane) * 8;
      bf16x8 bh = *(const bf16x8*)(Whi + foff);
      bf16x8 bl = *(const bf16x8*)(Wlo + foff);
#pragma unroll
      for (int mt = 0; mt < 2; mt++) {
        acc[mt][nt] = __builtin_amdgcn_mfma_f32_16x16x32_bf16(ah[mt], bh, acc[mt][nt], 0, 0, 0);
        acc[mt][nt] = __builtin_amdgcn_mfma_f32_16x16x32_bf16(ah[mt], bl, acc[mt][nt], 0, 0, 0);
        acc[mt][nt] = __builtin_amdgcn_mfma_f32_16x16x32_bf16(al[mt], bh, acc[mt][nt], 0, 0, 0);
        acc[mt][nt] = __builtin_amdgcn_mfma_f32_16x16x32_bf16(al[mt], bl, acc[mt][nt], 0, 0, 0);
      }
    }
  }

  // epilogue: C/D layout col=lane&15, row=(lane>>4)*4+reg
  int ccol = lane & 15;
  int crow0 = (lane >> 4) * 4;
#pragma unroll
  for (int nt = 0; nt < 8; nt++) {
    int c = o0 + nt * 16 + ccol;
    float sc, cb;
    float b = bias[c];
    if (DOBN) {
      sc = gamma[c] * rsqrtf(var[c] + BN_EPS);
      cb = (b - mean[c]) * sc + beta[c];
    } else {
      sc = 1.0f;
      cb = b;
    }
#pragma unroll
    for (int mt = 0; mt < 2; mt++) {
#pragma unroll
      for (int r = 0; r < 4; r++) {
        float v = fmaf(acc[mt][nt][r], sc, cb);
        if (DORELU) v = fmaxf(v, 0.0f);
        size_t row = (size_t)(m0 + mt * 16 + crow0 + r);
        if (SPLIT_OUT) {
          unsigned short h_, l_;
          split_bf(v, h_, l_);
          Chi[row * O + c] = h_;
          Clo[row * O + c] = l_;
        } else {
          Cf[row * O + c] = v;
        }
      }
    }
  }
}

// ---------------- key-norm max per (graph, head) ----------------
__global__ __launch_bounds__(256) void knorm_kernel(const float* __restrict__ qkv,
                                                    float* __restrict__ kmax2) {
  int g = blockIdx.x >> 2;
  int h = blockIdx.x & 3;
  size_t gbase = (size_t)g * NPG;
  float best = 0.0f;
#pragma unroll
  for (int r = 0; r < 2; r++) {
    int j = r * 256 + threadIdx.x;
    const float* kp = &qkv[(gbase + j) * 384 + 128 + h * 32];
    float s = 0.0f;
#pragma unroll
    for (int i = 0; i < 8; i++) {
      float4 v = *(const float4*)(kp + i * 4);
      s = fmaf(v.x, v.x, s);
      s = fmaf(v.y, v.y, s);
      s = fmaf(v.z, v.z, s);
      s = fmaf(v.w, v.w, s);
    }
    best = fmaxf(best, s);
  }
#pragma unroll
  for (int off = 32; off >= 1; off >>= 1)
    best = fmaxf(best, __shfl_xor(best, off, 64));
  __shared__ float red[4];
  int wave = threadIdx.x >> 6;
  if ((threadIdx.x & 63) == 0) red[wave] = best;
  __syncthreads();
  if (threadIdx.x == 0) {
    float m = fmaxf(fmaxf(red[0], red[1]), fmaxf(red[2], red[3]));
    kmax2[blockIdx.x] = m;
  }
}

// ---------------- attention: lane-pair dim-split (R4 structure), split-bf16 output -----
__global__ __launch_bounds__(512, 4) void attn_kernel(const float* __restrict__ qkv,
                                                      const float* __restrict__ kmax2,
                                                      unsigned short* __restrict__ ohi,
                                                      unsigned short* __restrict__ olo) {
  int g = blockIdx.x >> 2;
  int h = blockIdx.x & 3;
  int t = threadIdx.x;
  int wave = t >> 6;
  int lane = t & 63;
  int pr = lane & 31;
  int hi16 = lane >> 5;
  size_t gbase = (size_t)g * NPG;

  const float cf = 0.17677669529663687f * 1.4426950408889634f;

  __shared__ float sk[128][36];
  __shared__ float sv[128][36];

  int qA = wave * 64 + pr;
  int qB = qA + 32;

  float a[16], b[16];
  {
    const float* pA = &qkv[(gbase + qA) * 384 + h * 32 + hi16 * 16];
    const float* pB = &qkv[(gbase + qB) * 384 + h * 32 + hi16 * 16];
#pragma unroll
    for (int i = 0; i < 4; i++) {
      float4 vA = *(const float4*)(pA + i * 4);
      float4 vB = *(const float4*)(pB + i * 4);
      a[i * 4 + 0] = vA.x * cf; a[i * 4 + 1] = vA.y * cf;
      a[i * 4 + 2] = vA.z * cf; a[i * 4 + 3] = vA.w * cf;
      b[i * 4 + 0] = vB.x * cf; b[i * 4 + 1] = vB.y * cf;
      b[i * 4 + 2] = vB.z * cf; b[i * 4 + 3] = vB.w * cf;
    }
  }
  float na = 0.0f, nb = 0.0f;
#pragma unroll
  for (int d = 0; d < 16; d++) {
    na = fmaf(a[d], a[d], na);
    nb = fmaf(b[d], b[d], nb);
  }
  na += __shfl_xor(na, 32);
  nb += __shfl_xor(nb, 32);
  float km2 = kmax2[g * 4 + h];
  float MA = sqrtf(na * km2);
  float MB = sqrtf(nb * km2);

  float oA[16], oB[16];
#pragma unroll
  for (int d = 0; d < 16; d++) { oA[d] = 0.0f; oB[d] = 0.0f; }
  float lA = 0.0f, lB = 0.0f;

  int srow = t & 127;
  int ssel = t >> 7;
  int iskv = ssel >> 1;
  int seg = ssel & 1;

  for (int c = 0; c < 4; c++) {
    __syncthreads();
    {
      const float* gp = &qkv[(gbase + (size_t)(c * 128 + srow)) * 384 + 128 +
                             iskv * 128 + h * 32 + seg * 16];
      float* sp = iskv ? &sv[srow][seg * 16] : &sk[srow][seg * 16];
#pragma unroll
      for (int i = 0; i < 4; i++) *(float4*)(sp + i * 4) = *(const float4*)(gp + i * 4);
    }
    __syncthreads();
#pragma unroll 2
    for (int j = 0; j < 128; j++) {
      const float* kp = &sk[j][hi16 * 16];
      float4 k0 = *(const float4*)(kp);
      float4 k1 = *(const float4*)(kp + 4);
      float4 k2 = *(const float4*)(kp + 8);
      float4 k3 = *(const float4*)(kp + 12);
      float sa0 = fmaf(a[3], k0.w, fmaf(a[2], k0.z, fmaf(a[1], k0.y, a[0] * k0.x)));
      float sa1 = fmaf(a[7], k1.w, fmaf(a[6], k1.z, fmaf(a[5], k1.y, a[4] * k1.x)));
      float sa2 = fmaf(a[11], k2.w, fmaf(a[10], k2.z, fmaf(a[9], k2.y, a[8] * k2.x)));
      float sa3 = fmaf(a[15], k3.w, fmaf(a[14], k3.z, fmaf(a[13], k3.y, a[12] * k3.x)));
      float sb0 = fmaf(b[3], k0.w, fmaf(b[2], k0.z, fmaf(b[1], k0.y, b[0] * k0.x)));
      float sb1 = fmaf(b[7], k1.w, fmaf(b[6], k1.z, fmaf(b[5], k1.y, b[4] * k1.x)));
      float sb2 = fmaf(b[11], k2.w, fmaf(b[10], k2.z, fmaf(b[9], k2.y, b[8] * k2.x)));
      float sb3 = fmaf(b[15], k3.w, fmaf(b[14], k3.z, fmaf(b[13], k3.y, b[12] * k3.x)));
      float sa = (sa0 + sa1) + (sa2 + sa3);
      float sb = (sb0 + sb1) + (sb2 + sb3);
      sa += __shfl_xor(sa, 32);
      sb += __shfl_xor(sb, 32);
      float pa = __builtin_exp2f(sa - MA);
      float pb = __builtin_exp2f(sb - MB);
      lA += pa;
      lB += pb;
      const float* vp = &sv[j][hi16 * 16];
      float4 v0 = *(const float4*)(vp);
      float4 v1 = *(const float4*)(vp + 4);
      float4 v2 = *(const float4*)(vp + 8);
      float4 v3 = *(const float4*)(vp + 12);
      oA[0] = fmaf(pa, v0.x, oA[0]);   oA[1] = fmaf(pa, v0.y, oA[1]);
      oA[2] = fmaf(pa, v0.z, oA[2]);   oA[3] = fmaf(pa, v0.w, oA[3]);
      oA[4] = fmaf(pa, v1.x, oA[4]);   oA[5] = fmaf(pa, v1.y, oA[5]);
      oA[6] = fmaf(pa, v1.z, oA[6]);   oA[7] = fmaf(pa, v1.w, oA[7]);
      oA[8] = fmaf(pa, v2.x, oA[8]);   oA[9] = fmaf(pa, v2.y, oA[9]);
      oA[10] = fmaf(pa, v2.z, oA[10]); oA[11] = fmaf(pa, v2.w, oA[11]);
      oA[12] = fmaf(pa, v3.x, oA[12]); oA[13] = fmaf(pa, v3.y, oA[13]);
      oA[14] = fmaf(pa, v3.z, oA[14]); oA[15] = fmaf(pa, v3.w, oA[15]);
      oB[0] = fmaf(pb, v0.x, oB[0]);   oB[1] = fmaf(pb, v0.y, oB[1]);
      oB[2] = fmaf(pb, v0.z, oB[2]);   oB[3] = fmaf(pb, v0.w, oB[3]);
      oB[4] = fmaf(pb, v1.x, oB[4]);   oB[5] = fmaf(pb, v1.y, oB[5]);
      oB[6] = fmaf(pb, v1.z, oB[6]);   oB[7] = fmaf(pb, v1.w, oB[7]);
      oB[8] = fmaf(pb, v2.x, oB[8]);   oB[9] = fmaf(pb, v2.y, oB[9]);
      oB[10] = fmaf(pb, v2.z, oB[10]); oB[11] = fmaf(pb, v2.w, oB[11]);
      oB[12] = fmaf(pb, v3.x, oB[12]); oB[13] = fmaf(pb, v3.y, oB[13]);
      oB[14] = fmaf(pb, v3.z, oB[14]); oB[15] = fmaf(pb, v3.w, oB[15]);
    }
  }

  float iA = 1.0f / lA;
  float iB = 1.0f / lB;
  size_t baseA = (gbase + qA) * 128 + h * 32 + hi16 * 16;
  size_t baseB = (gbase + qB) * 128 + h * 32 + hi16 * 16;
  u16x8 vh, vl;
#pragma unroll
  for (int half = 0; half < 2; half++) {
#pragma unroll
    for (int j = 0; j < 8; j++) {
      unsigned short h_, l_;
      split_bf(oA[half * 8 + j] * iA, h_, l_);
      vh[j] = h_;
      vl[j] = l_;
    }
    *(u16x8*)(ohi + baseA + half * 8) = vh;
    *(u16x8*)(olo + baseA + half * 8) = vl;
#pragma unroll
    for (int j = 0; j < 8; j++) {
      unsigned short h_, l_;
      split_bf(oB[half * 8 + j] * iB, h_, l_);
      vh[j] = h_;
      vl[j] = l_;
    }
    *(u16x8*)(ohi + baseB + half * 8) = vh;
    *(u16x8*)(olo + baseB + half * 8) = vl;
  }
}

// ---------------- mean pool ----------------
__global__ __launch_bounds__(128) void pool_kernel(const float* __restrict__ fin,
                                                   float* __restrict__ emb) {
  int g = blockIdx.x, c = threadIdx.x;
  const float* p = fin + (size_t)g * NPG * HID + c;
  float s = 0.0f;
  for (int i = 0; i < NPG; i++) s += p[(size_t)i * HID];
  emb[g * HID + c] = s * (1.0f / NPG);
}

extern "C" void kernel_launch(void* const* d_in, const int* in_sizes, int n_in,
                              void* d_out, int out_size, void* d_ws, size_t ws_size,
                              hipStream_t stream) {
  (void)in_sizes; (void)n_in; (void)out_size; (void)ws_size;
  const float* x          = (const float*)d_in[0];
  const float* W0         = (const float*)d_in[1];
  const float* b0         = (const float*)d_in[2];
  const float* Wh         = (const float*)d_in[3];
  const float* bh         = (const float*)d_in[4];
  const float* bn_gamma   = (const float*)d_in[5];
  const float* bn_beta    = (const float*)d_in[6];
  const float* bn_mean    = (const float*)d_in[7];
  const float* bn_var     = (const float*)d_in[8];
  const float* attn_in_w  = (const float*)d_in[9];
  const float* attn_in_b  = (const float*)d_in[10];
  const float* attn_out_w = (const float*)d_in[11];
  const float* attn_out_b = (const float*)d_in[12];
  const int* edge_index   = (const int*)d_in[13];
  const int* src = edge_index;
  const int* dst = edge_index + N_EDGES;

  char* ws = (char*)d_ws;
  size_t off = 0;
  auto alloc = [&](size_t bytes) -> void* {
    void* p = ws + off;
    off += (bytes + 255) & ~(size_t)255;
    return p;
  };
  int*   deg     = (int*)alloc((size_t)N_NODES * 4);
  int*   offsets = (int*)alloc((size_t)(N_NODES + 1) * 4);
  int*   cursor  = (int*)alloc((size_t)N_NODES * 4);
  int*   csr     = (int*)alloc((size_t)N_EDGES * 4);
  float* dis     = (float*)alloc((size_t)N_NODES * 4);
  float* bufA    = (float*)alloc((size_t)N_NODES * HID * 4);   // h fp32; later f_hi/f_lo
  unsigned short* zhi = (unsigned short*)alloc((size_t)N_NODES * HID * 2);  // also o_hi
  unsigned short* zlo = (unsigned short*)alloc((size_t)N_NODES * HID * 2);  // also o_lo
  float* qkvb    = (float*)alloc((size_t)N_NODES * 384 * 4);
  float* kmax2   = (float*)alloc((size_t)N_GRAPHS * 4 * 4);
  // weight fragments (hi/lo)
  unsigned short* w0h = (unsigned short*)alloc(8192 * 2);
  unsigned short* w0l = (unsigned short*)alloc(8192 * 2);
  unsigned short* whh[3], *whl[3];
  for (int i = 0; i < 3; i++) {
    whh[i] = (unsigned short*)alloc(16384 * 2);
    whl[i] = (unsigned short*)alloc(16384 * 2);
  }
  unsigned short* wqh = (unsigned short*)alloc(49152 * 2);
  unsigned short* wql = (unsigned short*)alloc(49152 * 2);
  unsigned short* woh = (unsigned short*)alloc(16384 * 2);
  unsigned short* wol = (unsigned short*)alloc(16384 * 2);

  unsigned short* fhi = (unsigned short*)bufA;                 // reuse bufA for f split
  unsigned short* flo = fhi + (size_t)N_NODES * HID;

  float* fin = (float*)d_out;                       // [N, HID]
  float* emb = fin + (size_t)N_NODES * HID;         // [G, HID]

  hipMemsetAsync(deg, 0, (size_t)N_NODES * 4, stream);
  hist_kernel<<<N_EDGES / 256, 256, 0, stream>>>(dst, deg);
  dis_kernel<<<N_NODES / 256, 256, 0, stream>>>(deg, dis);
  scan_kernel<<<1, 1024, 0, stream>>>(deg, offsets, cursor);
  fill_kernel<<<N_EDGES / 256, 256, 0, stream>>>(src, dst, cursor, csr);

  // weight prep
  wprep_kernel<false><<<4, 256, 0, stream>>>(W0, 64, 128, w0h, w0l);
  for (int i = 0; i < 3; i++)
    wprep_kernel<false><<<8, 256, 0, stream>>>(Wh + (size_t)i * HID * HID, 128, 128,
                                               whh[i], whl[i]);
  wprep_kernel<true><<<24, 256, 0, stream>>>(attn_in_w, 128, 384, wqh, wql);
  wprep_kernel<true><<<8, 256, 0, stream>>>(attn_out_w, 128, 128, woh, wol);

  dim3 ggrid(N_NODES / 128, 1);
  // layer 0
  agg64_kernel<<<N_NODES / 4, 256, 0, stream>>>(x, dis, offsets, csr, zhi, zlo);
  gemm_mfma<64, 128, true, true, false><<<ggrid, 256, 0, stream>>>(
      zhi, zlo, w0h, w0l, b0, bn_gamma, bn_beta, bn_mean, bn_var, bufA, nullptr, nullptr);
  // layers 1,2 (fp32 h out)
  for (int L = 0; L < 2; L++) {
    agg128_kernel<<<N_NODES / 4, 256, 0, stream>>>(bufA, dis, offsets, csr, zhi, zlo);
    gemm_mfma<128, 128, true, true, false><<<ggrid, 256, 0, stream>>>(
        zhi, zlo, whh[L], whl[L], bh + (size_t)L * HID,
        bn_gamma + (size_t)(L + 1) * HID, bn_beta + (size_t)(L + 1) * HID,
        bn_mean + (size_t)(L + 1) * HID, bn_var + (size_t)(L + 1) * HID,
        bufA, nullptr, nullptr);
  }
  // layer 3 -> f split (into bufA region; bufA fp32 is dead after this agg)
  agg128_kernel<<<N_NODES / 4, 256, 0, stream>>>(bufA, dis, offsets, csr, zhi, zlo);
  gemm_mfma<128, 128, true, true, true><<<ggrid, 256, 0, stream>>>(
      zhi, zlo, whh[2], whl[2], bh + (size_t)2 * HID,
      bn_gamma + (size_t)3 * HID, bn_beta + (size_t)3 * HID,
      bn_mean + (size_t)3 * HID, bn_var + (size_t)3 * HID,
      nullptr, fhi, flo);
  // qkv = f @ attn_in_w^T + b
  dim3 qgrid(N_NODES / 128, 3);
  gemm_mfma<128, 384, false, false, false><<<qgrid, 256, 0, stream>>>(
      fhi, flo, wqh, wql, attn_in_b, nullptr, nullptr, nullptr, nullptr,
      qkvb, nullptr, nullptr);
  // attention -> o split (reuse z buffers; z is dead after layer-3 gemm)
  knorm_kernel<<<N_GRAPHS * 4, 256, 0, stream>>>(qkvb, kmax2);
  attn_kernel<<<N_GRAPHS * 4, 512, 0, stream>>>(qkvb, kmax2, zhi, zlo);
  // final = o @ attn_out_w^T + b
  gemm_mfma<128, 128, false, false, false><<<ggrid, 256, 0, stream>>>(
      zhi, zlo, woh, wol, attn_out_b, nullptr, nullptr, nullptr, nullptr,
      fin, nullptr, nullptr);
  pool_kernel<<<N_GRAPHS, 128, 0, stream>>>(fin, emb);
}

// Round 6
// 997.243 us; speedup vs baseline: 1.2812x; 1.1549x over previous
//
#include <hip/hip_runtime.h>
#include <hip/hip_bf16.h>
#include <cstdint>
#include <cstddef>

#define N_NODES 65536
#define N_EDGES 1048576
#define N_GRAPHS 128
#define NPG 512
#define IN_DIM 64
#define HID 128
#define BN_EPS 1e-5f

typedef __attribute__((ext_vector_type(8))) short bf16x8;
typedef __attribute__((ext_vector_type(4))) float f32x4;
typedef __attribute__((ext_vector_type(8))) unsigned short u16x8;

// ---- bf16 helpers (RNE, matches v_cvt) ----
__device__ inline unsigned short f2bf(float f) {
  unsigned u = __builtin_bit_cast(unsigned, f);
  u = u + 0x7fffu + ((u >> 16) & 1u);
  return (unsigned short)(u >> 16);
}
__device__ inline float bf2f(unsigned short h) {
  unsigned u = ((unsigned)h) << 16;
  return __builtin_bit_cast(float, u);
}
__device__ inline void split_bf(float v, unsigned short& hi, unsigned short& lo) {
  hi = f2bf(v);
  lo = f2bf(v - bf2f(hi));
}

// ---------------- CSR build ----------------
__global__ __launch_bounds__(256) void hist_kernel(const int* __restrict__ dst,
                                                   int* __restrict__ deg) {
  int e = blockIdx.x * 256 + threadIdx.x;
  if (e < N_EDGES) atomicAdd(&deg[dst[e]], 1);
}

__global__ __launch_bounds__(256) void dis_kernel(const int* __restrict__ deg,
                                                  float* __restrict__ dis) {
  int n = blockIdx.x * 256 + threadIdx.x;
  if (n < N_NODES) dis[n] = 1.0f / sqrtf((float)deg[n] + 1.0f);
}

__global__ __launch_bounds__(1024) void scan_kernel(const int* __restrict__ deg,
                                                    int* __restrict__ offsets,
                                                    int* __restrict__ cursor) {
  __shared__ int sums[1024];
  int t = threadIdx.x;
  int base = t * 64;
  const int4* dp = (const int4*)(deg + base);
  int s = 0;
#pragma unroll
  for (int i = 0; i < 16; i++) {
    int4 v = dp[i];
    s += v.x + v.y + v.z + v.w;
  }
  sums[t] = s;
  __syncthreads();
  for (int off = 1; off < 1024; off <<= 1) {
    int v = (t >= off) ? sums[t - off] : 0;
    __syncthreads();
    sums[t] += v;
    __syncthreads();
  }
  int run = (t == 0) ? 0 : sums[t - 1];
#pragma unroll
  for (int i = 0; i < 16; i++) {
    int4 v = dp[i];
    int idx = base + i * 4;
    offsets[idx] = run; cursor[idx] = run; run += v.x;
    offsets[idx + 1] = run; cursor[idx + 1] = run; run += v.y;
    offsets[idx + 2] = run; cursor[idx + 2] = run; run += v.z;
    offsets[idx + 3] = run; cursor[idx + 3] = run; run += v.w;
  }
  if (t == 1023) offsets[N_NODES] = run;
}

__global__ __launch_bounds__(256) void fill_kernel(const int* __restrict__ src,
                                                   const int* __restrict__ dst,
                                                   int* __restrict__ cursor,
                                                   int* __restrict__ csr) {
  int e = blockIdx.x * 256 + threadIdx.x;
  if (e < N_EDGES) {
    int d = dst[e];
    int slot = atomicAdd(&cursor[d], 1);
    csr[slot] = src[e];
  }
}

// ---------------- aggregation (gather over CSR), chunk-4 prefetch, split-bf16 out ------
__global__ __launch_bounds__(256) void agg64_kernel(const float* __restrict__ x,
                                                    const float* __restrict__ dis,
                                                    const int* __restrict__ offsets,
                                                    const int* __restrict__ csr,
                                                    unsigned short* __restrict__ zhi,
                                                    unsigned short* __restrict__ zlo) {
  int node = blockIdx.x * 4 + (threadIdx.x >> 6);
  int lane = threadIdx.x & 63;
  float dn = dis[node];
  float acc = x[(size_t)node * 64 + lane] * dn * dn;
  int beg = offsets[node], end = offsets[node + 1];
  int k = beg;
  for (; k + 4 <= end; k += 4) {
    int s0 = csr[k], s1 = csr[k + 1], s2 = csr[k + 2], s3 = csr[k + 3];
    float w0 = dn * dis[s0], w1 = dn * dis[s1], w2 = dn * dis[s2], w3 = dn * dis[s3];
    float v0 = x[(size_t)s0 * 64 + lane];
    float v1 = x[(size_t)s1 * 64 + lane];
    float v2 = x[(size_t)s2 * 64 + lane];
    float v3 = x[(size_t)s3 * 64 + lane];
    acc = fmaf(w0, v0, acc);
    acc = fmaf(w1, v1, acc);
    acc = fmaf(w2, v2, acc);
    acc = fmaf(w3, v3, acc);
  }
  for (; k < end; k++) {
    int s = csr[k];
    acc = fmaf(dn * dis[s], x[(size_t)s * 64 + lane], acc);
  }
  unsigned short h_, l_;
  split_bf(acc, h_, l_);
  zhi[(size_t)node * 64 + lane] = h_;
  zlo[(size_t)node * 64 + lane] = l_;
}

__global__ __launch_bounds__(256) void agg128_kernel(const float* __restrict__ h,
                                                     const float* __restrict__ dis,
                                                     const int* __restrict__ offsets,
                                                     const int* __restrict__ csr,
                                                     unsigned short* __restrict__ zhi,
                                                     unsigned short* __restrict__ zlo) {
  int node = blockIdx.x * 4 + (threadIdx.x >> 6);
  int lane = threadIdx.x & 63;
  float dn = dis[node];
  float sn = dn * dn;
  const float* hr = h + (size_t)node * 128;
  float a0 = hr[lane] * sn;
  float a1 = hr[lane + 64] * sn;
  int beg = offsets[node], end = offsets[node + 1];
  int k = beg;
  for (; k + 4 <= end; k += 4) {
    int s0 = csr[k], s1 = csr[k + 1], s2 = csr[k + 2], s3 = csr[k + 3];
    float w0 = dn * dis[s0], w1 = dn * dis[s1], w2 = dn * dis[s2], w3 = dn * dis[s3];
    const float* p0 = h + (size_t)s0 * 128;
    const float* p1 = h + (size_t)s1 * 128;
    const float* p2 = h + (size_t)s2 * 128;
    const float* p3 = h + (size_t)s3 * 128;
    float u0 = p0[lane], d0 = p0[lane + 64];
    float u1 = p1[lane], d1 = p1[lane + 64];
    float u2 = p2[lane], d2 = p2[lane + 64];
    float u3 = p3[lane], d3 = p3[lane + 64];
    a0 = fmaf(w0, u0, a0); a1 = fmaf(w0, d0, a1);
    a0 = fmaf(w1, u1, a0); a1 = fmaf(w1, d1, a1);
    a0 = fmaf(w2, u2, a0); a1 = fmaf(w2, d2, a1);
    a0 = fmaf(w3, u3, a0); a1 = fmaf(w3, d3, a1);
  }
  for (; k < end; k++) {
    int s = csr[k];
    float w = dn * dis[s];
    const float* hs = h + (size_t)s * 128;
    a0 = fmaf(w, hs[lane], a0);
    a1 = fmaf(w, hs[lane + 64], a1);
  }
  unsigned short h0, l0, h1, l1;
  split_bf(a0, h0, l0);
  split_bf(a1, h1, l1);
  zhi[(size_t)node * 128 + lane] = h0;
  zlo[(size_t)node * 128 + lane] = l0;
  zhi[(size_t)node * 128 + lane + 64] = h1;
  zlo[(size_t)node * 128 + lane + 64] = l1;
}

// ---------------- weight prep: fp32 W -> bf16 hi/lo in b-fragment layout ----------------
template <bool TRANS>
__global__ __launch_bounds__(256) void wprep_kernel(const float* __restrict__ W, int K, int O,
                                                    unsigned short* __restrict__ hi,
                                                    unsigned short* __restrict__ lo) {
  int idx = blockIdx.x * 256 + threadIdx.x;
  int KC = K / 32;
  int total = (O / 16) * KC * 64;
  if (idx >= total) return;
  int lane = idx & 63;
  int rest = idx >> 6;
  int kc = rest % KC;
  int nt = rest / KC;
  int n = nt * 16 + (lane & 15);
  int kb = kc * 32 + (lane >> 4) * 8;
  unsigned short* hp = hi + (size_t)idx * 8;
  unsigned short* lp = lo + (size_t)idx * 8;
#pragma unroll
  for (int j = 0; j < 8; j++) {
    int k = kb + j;
    float v = TRANS ? W[(size_t)n * K + k] : W[(size_t)k * O + n];
    unsigned short h_, l_;
    split_bf(v, h_, l_);
    hp[j] = h_;
    lp[j] = l_;
  }
}

// ---------------- MFMA GEMM (R5 structure, unchanged) ----------------
template <int K, int O, bool DOBN, bool DORELU, bool SPLIT_OUT>
__global__ __launch_bounds__(256) void gemm_mfma(
    const unsigned short* __restrict__ Ahi, const unsigned short* __restrict__ Alo,
    const unsigned short* __restrict__ Whi, const unsigned short* __restrict__ Wlo,
    const float* __restrict__ bias,
    const float* __restrict__ gamma, const float* __restrict__ beta,
    const float* __restrict__ mean, const float* __restrict__ var,
    float* __restrict__ Cf, unsigned short* __restrict__ Chi,
    unsigned short* __restrict__ Clo) {
  constexpr int KC = K / 32;
  int wave = threadIdx.x >> 6;
  int lane = threadIdx.x & 63;
  int m0 = blockIdx.x * 128 + wave * 32;
  int o0 = blockIdx.y * 128;
  int mrow = lane & 15;
  int kseg = (lane >> 4) * 8;

  f32x4 acc[2][8];
#pragma unroll
  for (int mt = 0; mt < 2; mt++)
#pragma unroll
    for (int nt = 0; nt < 8; nt++) acc[mt][nt] = (f32x4)0.0f;

#pragma unroll
  for (int kc = 0; kc < KC; kc++) {
    bf16x8 ah[2], al[2];
#pragma unroll
    for (int mt = 0; mt < 2; mt++) {
      size_t aoff = (size_t)(m0 + mt * 16 + mrow) * K + kc * 32 + kseg;
      ah[mt] = *(const bf16x8*)(Ahi + aoff);
      al[mt] = *(const bf16x8*)(Alo + aoff);
    }
#pragma unroll
    for (int nt = 0; nt < 8; nt++) {
      size_t foff = (((size_t)(blockIdx.y * 8 + nt) * KC + kc) * 64 + lane) * 8;
      bf16x8 bh = *(const bf16x8*)(Whi + foff);
      bf16x8 bl = *(const bf16x8*)(Wlo + foff);
#pragma unroll
      for (int mt = 0; mt < 2; mt++) {
        acc[mt][nt] = __builtin_amdgcn_mfma_f32_16x16x32_bf16(ah[mt], bh, acc[mt][nt], 0, 0, 0);
        acc[mt][nt] = __builtin_amdgcn_mfma_f32_16x16x32_bf16(ah[mt], bl, acc[mt][nt], 0, 0, 0);
        acc[mt][nt] = __builtin_amdgcn_mfma_f32_16x16x32_bf16(al[mt], bh, acc[mt][nt], 0, 0, 0);
        acc[mt][nt] = __builtin_amdgcn_mfma_f32_16x16x32_bf16(al[mt], bl, acc[mt][nt], 0, 0, 0);
      }
    }
  }

  int ccol = lane & 15;
  int crow0 = (lane >> 4) * 4;
#pragma unroll
  for (int nt = 0; nt < 8; nt++) {
    int c = o0 + nt * 16 + ccol;
    float sc, cb;
    float b = bias[c];
    if (DOBN) {
      sc = gamma[c] * rsqrtf(var[c] + BN_EPS);
      cb = (b - mean[c]) * sc + beta[c];
    } else {
      sc = 1.0f;
      cb = b;
    }
#pragma unroll
    for (int mt = 0; mt < 2; mt++) {
#pragma unroll
      for (int r = 0; r < 4; r++) {
        float v = fmaf(acc[mt][nt][r], sc, cb);
        if (DORELU) v = fmaxf(v, 0.0f);
        size_t row = (size_t)(m0 + mt * 16 + crow0 + r);
        if (SPLIT_OUT) {
          unsigned short h_, l_;
          split_bf(v, h_, l_);
          Chi[row * O + c] = h_;
          Clo[row * O + c] = l_;
        } else {
          Cf[row * O + c] = v;
        }
      }
    }
  }
}

// ---------------- key-norm max per (graph, head) ----------------
__global__ __launch_bounds__(256) void knorm_kernel(const float* __restrict__ qkv,
                                                    float* __restrict__ kmax2) {
  int g = blockIdx.x >> 2;
  int h = blockIdx.x & 3;
  size_t gbase = (size_t)g * NPG;
  float best = 0.0f;
#pragma unroll
  for (int r = 0; r < 2; r++) {
    int j = r * 256 + threadIdx.x;
    const float* kp = &qkv[(gbase + j) * 384 + 128 + h * 32];
    float s = 0.0f;
#pragma unroll
    for (int i = 0; i < 8; i++) {
      float4 v = *(const float4*)(kp + i * 4);
      s = fmaf(v.x, v.x, s);
      s = fmaf(v.y, v.y, s);
      s = fmaf(v.z, v.z, s);
      s = fmaf(v.w, v.w, s);
    }
    best = fmaxf(best, s);
  }
#pragma unroll
  for (int off = 32; off >= 1; off >>= 1)
    best = fmaxf(best, __shfl_xor(best, off, 64));
  __shared__ float red[4];
  int wave = threadIdx.x >> 6;
  if ((threadIdx.x & 63) == 0) red[wave] = best;
  __syncthreads();
  if (threadIdx.x == 0) {
    float m = fmaxf(fmaxf(red[0], red[1]), fmaxf(red[2], red[3]));
    kmax2[blockIdx.x] = m;
  }
}

// ---------------- attention: 4 queries/lane, dim-split, single pass ---------------------
// grid: 128 g x 4 h = 512 blocks; block 256 thr = 4 waves.
// Wave w owns queries [w*128, w*128+128): lane pr=lane&31 handles q = w*128+m*32+pr
// (m=0..3); lane<32 holds dims [0:16), lane>=32 dims [16:32). Per key: 128 B LDS read
// feeds 128 FMA (1.0 MAC/B, 2x R4). State: 4x16 q + 4x16 o = 128 f -> ~180 VGPR,
// needs the 256-cap from (256,2); spill tripwire = WRITE_SIZE >> 33 MB.
__global__ __launch_bounds__(256, 2) void attn_kernel(const float* __restrict__ qkv,
                                                      const float* __restrict__ kmax2,
                                                      unsigned short* __restrict__ ohi,
                                                      unsigned short* __restrict__ olo) {
  int g = blockIdx.x >> 2;
  int h = blockIdx.x & 3;
  int t = threadIdx.x;
  int wave = t >> 6;
  int lane = t & 63;
  int pr = lane & 31;
  int hi16 = lane >> 5;
  size_t gbase = (size_t)g * NPG;

  const float cf = 0.17677669529663687f * 1.4426950408889634f;  // scale*log2(e)

  __shared__ float sk[128][36];
  __shared__ float sv[128][36];

  float q[4][16], o[4][16];
  float M[4], l[4];
  float km2 = kmax2[g * 4 + h];
#pragma unroll
  for (int m = 0; m < 4; m++) {
    int qi = wave * 128 + m * 32 + pr;
    const float* qp = &qkv[(gbase + qi) * 384 + h * 32 + hi16 * 16];
    float n = 0.0f;
#pragma unroll
    for (int i = 0; i < 4; i++) {
      float4 v = *(const float4*)(qp + i * 4);
      q[m][i * 4 + 0] = v.x * cf;
      q[m][i * 4 + 1] = v.y * cf;
      q[m][i * 4 + 2] = v.z * cf;
      q[m][i * 4 + 3] = v.w * cf;
    }
#pragma unroll
    for (int d = 0; d < 16; d++) n = fmaf(q[m][d], q[m][d], n);
    n += __shfl_xor(n, 32);
    M[m] = sqrtf(n * km2);  // Cauchy-Schwarz bound (log2 domain), >= max score
    l[m] = 0.0f;
#pragma unroll
    for (int d = 0; d < 16; d++) o[m][d] = 0.0f;
  }

  int srow = t & 127;  // staging: thread stages one 32-float row of k or v
  int iskv = t >> 7;

  for (int c = 0; c < 4; c++) {
    __syncthreads();
    {
      const float* gp = &qkv[(gbase + (size_t)(c * 128 + srow)) * 384 + 128 +
                             iskv * 128 + h * 32];
      float* sp = iskv ? &sv[srow][0] : &sk[srow][0];
#pragma unroll
      for (int i = 0; i < 8; i++) *(float4*)(sp + i * 4) = *(const float4*)(gp + i * 4);
    }
    __syncthreads();
#pragma unroll 2
    for (int j = 0; j < 128; j++) {
      const float* kp = &sk[j][hi16 * 16];
      float4 k0 = *(const float4*)(kp);
      float4 k1 = *(const float4*)(kp + 4);
      float4 k2 = *(const float4*)(kp + 8);
      float4 k3 = *(const float4*)(kp + 12);
      float p[4];
#pragma unroll
      for (int m = 0; m < 4; m++) {
        float s0 = fmaf(q[m][3], k0.w, fmaf(q[m][2], k0.z, fmaf(q[m][1], k0.y, q[m][0] * k0.x)));
        float s1 = fmaf(q[m][7], k1.w, fmaf(q[m][6], k1.z, fmaf(q[m][5], k1.y, q[m][4] * k1.x)));
        float s2 = fmaf(q[m][11], k2.w, fmaf(q[m][10], k2.z, fmaf(q[m][9], k2.y, q[m][8] * k2.x)));
        float s3 = fmaf(q[m][15], k3.w, fmaf(q[m][14], k3.z, fmaf(q[m][13], k3.y, q[m][12] * k3.x)));
        float s = (s0 + s1) + (s2 + s3);
        s += __shfl_xor(s, 32);  // partner dim-half
        p[m] = __builtin_exp2f(s - M[m]);
        l[m] += p[m];
      }
      const float* vp = &sv[j][hi16 * 16];
      float4 v0 = *(const float4*)(vp);
      float4 v1 = *(const float4*)(vp + 4);
      float4 v2 = *(const float4*)(vp + 8);
      float4 v3 = *(const float4*)(vp + 12);
#pragma unroll
      for (int m = 0; m < 4; m++) {
        float pm = p[m];
        o[m][0] = fmaf(pm, v0.x, o[m][0]);   o[m][1] = fmaf(pm, v0.y, o[m][1]);
        o[m][2] = fmaf(pm, v0.z, o[m][2]);   o[m][3] = fmaf(pm, v0.w, o[m][3]);
        o[m][4] = fmaf(pm, v1.x, o[m][4]);   o[m][5] = fmaf(pm, v1.y, o[m][5]);
        o[m][6] = fmaf(pm, v1.z, o[m][6]);   o[m][7] = fmaf(pm, v1.w, o[m][7]);
        o[m][8] = fmaf(pm, v2.x, o[m][8]);   o[m][9] = fmaf(pm, v2.y, o[m][9]);
        o[m][10] = fmaf(pm, v2.z, o[m][10]); o[m][11] = fmaf(pm, v2.w, o[m][11]);
        o[m][12] = fmaf(pm, v3.x, o[m][12]); o[m][13] = fmaf(pm, v3.y, o[m][13]);
        o[m][14] = fmaf(pm, v3.z, o[m][14]); o[m][15] = fmaf(pm, v3.w, o[m][15]);
      }
    }
  }

#pragma unroll
  for (int m = 0; m < 4; m++) {
    float inv = 1.0f / l[m];
    int qi = wave * 128 + m * 32 + pr;
    size_t base = (gbase + qi) * 128 + h * 32 + hi16 * 16;
    u16x8 vh, vl;
#pragma unroll
    for (int half = 0; half < 2; half++) {
#pragma unroll
      for (int j2 = 0; j2 < 8; j2++) {
        unsigned short h_, l_;
        split_bf(o[m][half * 8 + j2] * inv, h_, l_);
        vh[j2] = h_;
        vl[j2] = l_;
      }
      *(u16x8*)(ohi + base + half * 8) = vh;
      *(u16x8*)(olo + base + half * 8) = vl;
    }
  }
}

// ---------------- mean pool ----------------
__global__ __launch_bounds__(128) void pool_kernel(const float* __restrict__ fin,
                                                   float* __restrict__ emb) {
  int g = blockIdx.x, c = threadIdx.x;
  const float* p = fin + (size_t)g * NPG * HID + c;
  float s = 0.0f;
  for (int i = 0; i < NPG; i++) s += p[(size_t)i * HID];
  emb[g * HID + c] = s * (1.0f / NPG);
}

extern "C" void kernel_launch(void* const* d_in, const int* in_sizes, int n_in,
                              void* d_out, int out_size, void* d_ws, size_t ws_size,
                              hipStream_t stream) {
  (void)in_sizes; (void)n_in; (void)out_size; (void)ws_size;
  const float* x          = (const float*)d_in[0];
  const float* W0         = (const float*)d_in[1];
  const float* b0         = (const float*)d_in[2];
  const float* Wh         = (const float*)d_in[3];
  const float* bh         = (const float*)d_in[4];
  const float* bn_gamma   = (const float*)d_in[5];
  const float* bn_beta    = (const float*)d_in[6];
  const float* bn_mean    = (const float*)d_in[7];
  const float* bn_var     = (const float*)d_in[8];
  const float* attn_in_w  = (const float*)d_in[9];
  const float* attn_in_b  = (const float*)d_in[10];
  const float* attn_out_w = (const float*)d_in[11];
  const float* attn_out_b = (const float*)d_in[12];
  const int* edge_index   = (const int*)d_in[13];
  const int* src = edge_index;
  const int* dst = edge_index + N_EDGES;

  char* ws = (char*)d_ws;
  size_t off = 0;
  auto alloc = [&](size_t bytes) -> void* {
    void* p = ws + off;
    off += (bytes + 255) & ~(size_t)255;
    return p;
  };
  int*   deg     = (int*)alloc((size_t)N_NODES * 4);
  int*   offsets = (int*)alloc((size_t)(N_NODES + 1) * 4);
  int*   cursor  = (int*)alloc((size_t)N_NODES * 4);
  int*   csr     = (int*)alloc((size_t)N_EDGES * 4);
  float* dis     = (float*)alloc((size_t)N_NODES * 4);
  float* bufA    = (float*)alloc((size_t)N_NODES * HID * 4);   // h fp32; later f_hi/f_lo
  unsigned short* zhi = (unsigned short*)alloc((size_t)N_NODES * HID * 2);  // also o_hi
  unsigned short* zlo = (unsigned short*)alloc((size_t)N_NODES * HID * 2);  // also o_lo
  float* qkvb    = (float*)alloc((size_t)N_NODES * 384 * 4);
  float* kmax2   = (float*)alloc((size_t)N_GRAPHS * 4 * 4);
  unsigned short* w0h = (unsigned short*)alloc(8192 * 2);
  unsigned short* w0l = (unsigned short*)alloc(8192 * 2);
  unsigned short* whh[3], *whl[3];
  for (int i = 0; i < 3; i++) {
    whh[i] = (unsigned short*)alloc(16384 * 2);
    whl[i] = (unsigned short*)alloc(16384 * 2);
  }
  unsigned short* wqh = (unsigned short*)alloc(49152 * 2);
  unsigned short* wql = (unsigned short*)alloc(49152 * 2);
  unsigned short* woh = (unsigned short*)alloc(16384 * 2);
  unsigned short* wol = (unsigned short*)alloc(16384 * 2);

  unsigned short* fhi = (unsigned short*)bufA;
  unsigned short* flo = fhi + (size_t)N_NODES * HID;

  float* fin = (float*)d_out;                       // [N, HID]
  float* emb = fin + (size_t)N_NODES * HID;         // [G, HID]

  hipMemsetAsync(deg, 0, (size_t)N_NODES * 4, stream);
  hist_kernel<<<N_EDGES / 256, 256, 0, stream>>>(dst, deg);
  dis_kernel<<<N_NODES / 256, 256, 0, stream>>>(deg, dis);
  scan_kernel<<<1, 1024, 0, stream>>>(deg, offsets, cursor);
  fill_kernel<<<N_EDGES / 256, 256, 0, stream>>>(src, dst, cursor, csr);

  wprep_kernel<false><<<4, 256, 0, stream>>>(W0, 64, 128, w0h, w0l);
  for (int i = 0; i < 3; i++)
    wprep_kernel<false><<<8, 256, 0, stream>>>(Wh + (size_t)i * HID * HID, 128, 128,
                                               whh[i], whl[i]);
  wprep_kernel<true><<<24, 256, 0, stream>>>(attn_in_w, 128, 384, wqh, wql);
  wprep_kernel<true><<<8, 256, 0, stream>>>(attn_out_w, 128, 128, woh, wol);

  dim3 ggrid(N_NODES / 128, 1);
  agg64_kernel<<<N_NODES / 4, 256, 0, stream>>>(x, dis, offsets, csr, zhi, zlo);
  gemm_mfma<64, 128, true, true, false><<<ggrid, 256, 0, stream>>>(
      zhi, zlo, w0h, w0l, b0, bn_gamma, bn_beta, bn_mean, bn_var, bufA, nullptr, nullptr);
  for (int L = 0; L < 2; L++) {
    agg128_kernel<<<N_NODES / 4, 256, 0, stream>>>(bufA, dis, offsets, csr, zhi, zlo);
    gemm_mfma<128, 128, true, true, false><<<ggrid, 256, 0, stream>>>(
        zhi, zlo, whh[L], whl[L], bh + (size_t)L * HID,
        bn_gamma + (size_t)(L + 1) * HID, bn_beta + (size_t)(L + 1) * HID,
        bn_mean + (size_t)(L + 1) * HID, bn_var + (size_t)(L + 1) * HID,
        bufA, nullptr, nullptr);
  }
  agg128_kernel<<<N_NODES / 4, 256, 0, stream>>>(bufA, dis, offsets, csr, zhi, zlo);
  gemm_mfma<128, 128, true, true, true><<<ggrid, 256, 0, stream>>>(
      zhi, zlo, whh[2], whl[2], bh + (size_t)2 * HID,
      bn_gamma + (size_t)3 * HID, bn_beta + (size_t)3 * HID,
      bn_mean + (size_t)3 * HID, bn_var + (size_t)3 * HID,
      nullptr, fhi, flo);
  dim3 qgrid(N_NODES / 128, 3);
  gemm_mfma<128, 384, false, false, false><<<qgrid, 256, 0, stream>>>(
      fhi, flo, wqh, wql, attn_in_b, nullptr, nullptr, nullptr, nullptr,
      qkvb, nullptr, nullptr);
  knorm_kernel<<<N_GRAPHS * 4, 256, 0, stream>>>(qkvb, kmax2);
  attn_kernel<<<N_GRAPHS * 4, 256, 0, stream>>>(qkvb, kmax2, zhi, zlo);
  gemm_mfma<128, 128, false, false, false><<<ggrid, 256, 0, stream>>>(
      zhi, zlo, woh, wol, attn_out_b, nullptr, nullptr, nullptr, nullptr,
      fin, nullptr, nullptr);
  pool_kernel<<<N_GRAPHS, 128, 0, stream>>>(fin, emb);
}

// Round 7
// 838.196 us; speedup vs baseline: 1.5243x; 1.1897x over previous
//
#include <hip/hip_runtime.h>
#include <hip/hip_bf16.h>
#include <cstdint>
#include <cstddef>

#define N_NODES 65536
#define N_EDGES 1048576
#define N_GRAPHS 128
#define NPG 512
#define IN_DIM 64
#define HID 128
#define BN_EPS 1e-5f

typedef __attribute__((ext_vector_type(8))) short bf16x8;
typedef __attribute__((ext_vector_type(4))) float f32x4;
typedef __attribute__((ext_vector_type(8))) unsigned short u16x8;

// ---- bf16 helpers (RNE, matches v_cvt) ----
__device__ inline unsigned short f2bf(float f) {
  unsigned u = __builtin_bit_cast(unsigned, f);
  u = u + 0x7fffu + ((u >> 16) & 1u);
  return (unsigned short)(u >> 16);
}
__device__ inline float bf2f(unsigned short h) {
  unsigned u = ((unsigned)h) << 16;
  return __builtin_bit_cast(float, u);
}
__device__ inline void split_bf(float v, unsigned short& hi, unsigned short& lo) {
  hi = f2bf(v);
  lo = f2bf(v - bf2f(hi));
}

// ---------------- CSR build ----------------
__global__ __launch_bounds__(256) void hist_kernel(const int* __restrict__ dst,
                                                   int* __restrict__ deg) {
  int e = blockIdx.x * 256 + threadIdx.x;
  if (e < N_EDGES) atomicAdd(&deg[dst[e]], 1);
}

__global__ __launch_bounds__(256) void dis_kernel(const int* __restrict__ deg,
                                                  float* __restrict__ dis) {
  int n = blockIdx.x * 256 + threadIdx.x;
  if (n < N_NODES) dis[n] = 1.0f / sqrtf((float)deg[n] + 1.0f);
}

__global__ __launch_bounds__(1024) void scan_kernel(const int* __restrict__ deg,
                                                    int* __restrict__ offsets,
                                                    int* __restrict__ cursor) {
  __shared__ int sums[1024];
  int t = threadIdx.x;
  int base = t * 64;
  const int4* dp = (const int4*)(deg + base);
  int s = 0;
#pragma unroll
  for (int i = 0; i < 16; i++) {
    int4 v = dp[i];
    s += v.x + v.y + v.z + v.w;
  }
  sums[t] = s;
  __syncthreads();
  for (int off = 1; off < 1024; off <<= 1) {
    int v = (t >= off) ? sums[t - off] : 0;
    __syncthreads();
    sums[t] += v;
    __syncthreads();
  }
  int run = (t == 0) ? 0 : sums[t - 1];
#pragma unroll
  for (int i = 0; i < 16; i++) {
    int4 v = dp[i];
    int idx = base + i * 4;
    offsets[idx] = run; cursor[idx] = run; run += v.x;
    offsets[idx + 1] = run; cursor[idx + 1] = run; run += v.y;
    offsets[idx + 2] = run; cursor[idx + 2] = run; run += v.z;
    offsets[idx + 3] = run; cursor[idx + 3] = run; run += v.w;
  }
  if (t == 1023) offsets[N_NODES] = run;
}

__global__ __launch_bounds__(256) void fill_kernel(const int* __restrict__ src,
                                                   const int* __restrict__ dst,
                                                   int* __restrict__ cursor,
                                                   int* __restrict__ csr) {
  int e = blockIdx.x * 256 + threadIdx.x;
  if (e < N_EDGES) {
    int d = dst[e];
    int slot = atomicAdd(&cursor[d], 1);
    csr[slot] = src[e];
  }
}

// ---------------- aggregation (gather over CSR), chunk-4 prefetch, split-bf16 out ------
__global__ __launch_bounds__(256) void agg64_kernel(const float* __restrict__ x,
                                                    const float* __restrict__ dis,
                                                    const int* __restrict__ offsets,
                                                    const int* __restrict__ csr,
                                                    unsigned short* __restrict__ zhi,
                                                    unsigned short* __restrict__ zlo) {
  int node = blockIdx.x * 4 + (threadIdx.x >> 6);
  int lane = threadIdx.x & 63;
  float dn = dis[node];
  float acc = x[(size_t)node * 64 + lane] * dn * dn;
  int beg = offsets[node], end = offsets[node + 1];
  int k = beg;
  for (; k + 4 <= end; k += 4) {
    int s0 = csr[k], s1 = csr[k + 1], s2 = csr[k + 2], s3 = csr[k + 3];
    float w0 = dn * dis[s0], w1 = dn * dis[s1], w2 = dn * dis[s2], w3 = dn * dis[s3];
    float v0 = x[(size_t)s0 * 64 + lane];
    float v1 = x[(size_t)s1 * 64 + lane];
    float v2 = x[(size_t)s2 * 64 + lane];
    float v3 = x[(size_t)s3 * 64 + lane];
    acc = fmaf(w0, v0, acc);
    acc = fmaf(w1, v1, acc);
    acc = fmaf(w2, v2, acc);
    acc = fmaf(w3, v3, acc);
  }
  for (; k < end; k++) {
    int s = csr[k];
    acc = fmaf(dn * dis[s], x[(size_t)s * 64 + lane], acc);
  }
  unsigned short h_, l_;
  split_bf(acc, h_, l_);
  zhi[(size_t)node * 64 + lane] = h_;
  zlo[(size_t)node * 64 + lane] = l_;
}

__global__ __launch_bounds__(256) void agg128_kernel(const float* __restrict__ h,
                                                     const float* __restrict__ dis,
                                                     const int* __restrict__ offsets,
                                                     const int* __restrict__ csr,
                                                     unsigned short* __restrict__ zhi,
                                                     unsigned short* __restrict__ zlo) {
  int node = blockIdx.x * 4 + (threadIdx.x >> 6);
  int lane = threadIdx.x & 63;
  float dn = dis[node];
  float sn = dn * dn;
  const float* hr = h + (size_t)node * 128;
  float a0 = hr[lane] * sn;
  float a1 = hr[lane + 64] * sn;
  int beg = offsets[node], end = offsets[node + 1];
  int k = beg;
  for (; k + 4 <= end; k += 4) {
    int s0 = csr[k], s1 = csr[k + 1], s2 = csr[k + 2], s3 = csr[k + 3];
    float w0 = dn * dis[s0], w1 = dn * dis[s1], w2 = dn * dis[s2], w3 = dn * dis[s3];
    const float* p0 = h + (size_t)s0 * 128;
    const float* p1 = h + (size_t)s1 * 128;
    const float* p2 = h + (size_t)s2 * 128;
    const float* p3 = h + (size_t)s3 * 128;
    float u0 = p0[lane], d0 = p0[lane + 64];
    float u1 = p1[lane], d1 = p1[lane + 64];
    float u2 = p2[lane], d2 = p2[lane + 64];
    float u3 = p3[lane], d3 = p3[lane + 64];
    a0 = fmaf(w0, u0, a0); a1 = fmaf(w0, d0, a1);
    a0 = fmaf(w1, u1, a0); a1 = fmaf(w1, d1, a1);
    a0 = fmaf(w2, u2, a0); a1 = fmaf(w2, d2, a1);
    a0 = fmaf(w3, u3, a0); a1 = fmaf(w3, d3, a1);
  }
  for (; k < end; k++) {
    int s = csr[k];
    float w = dn * dis[s];
    const float* hs = h + (size_t)s * 128;
    a0 = fmaf(w, hs[lane], a0);
    a1 = fmaf(w, hs[lane + 64], a1);
  }
  unsigned short h0, l0, h1, l1;
  split_bf(a0, h0, l0);
  split_bf(a1, h1, l1);
  zhi[(size_t)node * 128 + lane] = h0;
  zlo[(size_t)node * 128 + lane] = l0;
  zhi[(size_t)node * 128 + lane + 64] = h1;
  zlo[(size_t)node * 128 + lane + 64] = l1;
}

// ---------------- weight prep: fp32 W -> bf16 hi/lo in b-fragment layout ----------------
template <bool TRANS>
__global__ __launch_bounds__(256) void wprep_kernel(const float* __restrict__ W, int K, int O,
                                                    unsigned short* __restrict__ hi,
                                                    unsigned short* __restrict__ lo) {
  int idx = blockIdx.x * 256 + threadIdx.x;
  int KC = K / 32;
  int total = (O / 16) * KC * 64;
  if (idx >= total) return;
  int lane = idx & 63;
  int rest = idx >> 6;
  int kc = rest % KC;
  int nt = rest / KC;
  int n = nt * 16 + (lane & 15);
  int kb = kc * 32 + (lane >> 4) * 8;
  unsigned short* hp = hi + (size_t)idx * 8;
  unsigned short* lp = lo + (size_t)idx * 8;
#pragma unroll
  for (int j = 0; j < 8; j++) {
    int k = kb + j;
    float v = TRANS ? W[(size_t)n * K + k] : W[(size_t)k * O + n];
    unsigned short h_, l_;
    split_bf(v, h_, l_);
    hp[j] = h_;
    lp[j] = l_;
  }
}

// ---------------- MFMA GEMM (R5 structure, unchanged) ----------------
template <int K, int O, bool DOBN, bool DORELU, bool SPLIT_OUT>
__global__ __launch_bounds__(256) void gemm_mfma(
    const unsigned short* __restrict__ Ahi, const unsigned short* __restrict__ Alo,
    const unsigned short* __restrict__ Whi, const unsigned short* __restrict__ Wlo,
    const float* __restrict__ bias,
    const float* __restrict__ gamma, const float* __restrict__ beta,
    const float* __restrict__ mean, const float* __restrict__ var,
    float* __restrict__ Cf, unsigned short* __restrict__ Chi,
    unsigned short* __restrict__ Clo) {
  constexpr int KC = K / 32;
  int wave = threadIdx.x >> 6;
  int lane = threadIdx.x & 63;
  int m0 = blockIdx.x * 128 + wave * 32;
  int o0 = blockIdx.y * 128;
  int mrow = lane & 15;
  int kseg = (lane >> 4) * 8;

  f32x4 acc[2][8];
#pragma unroll
  for (int mt = 0; mt < 2; mt++)
#pragma unroll
    for (int nt = 0; nt < 8; nt++) acc[mt][nt] = (f32x4)0.0f;

#pragma unroll
  for (int kc = 0; kc < KC; kc++) {
    bf16x8 ah[2], al[2];
#pragma unroll
    for (int mt = 0; mt < 2; mt++) {
      size_t aoff = (size_t)(m0 + mt * 16 + mrow) * K + kc * 32 + kseg;
      ah[mt] = *(const bf16x8*)(Ahi + aoff);
      al[mt] = *(const bf16x8*)(Alo + aoff);
    }
#pragma unroll
    for (int nt = 0; nt < 8; nt++) {
      size_t foff = (((size_t)(blockIdx.y * 8 + nt) * KC + kc) * 64 + lane) * 8;
      bf16x8 bh = *(const bf16x8*)(Whi + foff);
      bf16x8 bl = *(const bf16x8*)(Wlo + foff);
#pragma unroll
      for (int mt = 0; mt < 2; mt++) {
        acc[mt][nt] = __builtin_amdgcn_mfma_f32_16x16x32_bf16(ah[mt], bh, acc[mt][nt], 0, 0, 0);
        acc[mt][nt] = __builtin_amdgcn_mfma_f32_16x16x32_bf16(ah[mt], bl, acc[mt][nt], 0, 0, 0);
        acc[mt][nt] = __builtin_amdgcn_mfma_f32_16x16x32_bf16(al[mt], bh, acc[mt][nt], 0, 0, 0);
        acc[mt][nt] = __builtin_amdgcn_mfma_f32_16x16x32_bf16(al[mt], bl, acc[mt][nt], 0, 0, 0);
      }
    }
  }

  int ccol = lane & 15;
  int crow0 = (lane >> 4) * 4;
#pragma unroll
  for (int nt = 0; nt < 8; nt++) {
    int c = o0 + nt * 16 + ccol;
    float sc, cb;
    float b = bias[c];
    if (DOBN) {
      sc = gamma[c] * rsqrtf(var[c] + BN_EPS);
      cb = (b - mean[c]) * sc + beta[c];
    } else {
      sc = 1.0f;
      cb = b;
    }
#pragma unroll
    for (int mt = 0; mt < 2; mt++) {
#pragma unroll
      for (int r = 0; r < 4; r++) {
        float v = fmaf(acc[mt][nt][r], sc, cb);
        if (DORELU) v = fmaxf(v, 0.0f);
        size_t row = (size_t)(m0 + mt * 16 + crow0 + r);
        if (SPLIT_OUT) {
          unsigned short h_, l_;
          split_bf(v, h_, l_);
          Chi[row * O + c] = h_;
          Clo[row * O + c] = l_;
        } else {
          Cf[row * O + c] = v;
        }
      }
    }
  }
}

// ---------------- key-norm max per (graph, head) ----------------
__global__ __launch_bounds__(256) void knorm_kernel(const float* __restrict__ qkv,
                                                    float* __restrict__ kmax2) {
  int g = blockIdx.x >> 2;
  int h = blockIdx.x & 3;
  size_t gbase = (size_t)g * NPG;
  float best = 0.0f;
#pragma unroll
  for (int r = 0; r < 2; r++) {
    int j = r * 256 + threadIdx.x;
    const float* kp = &qkv[(gbase + j) * 384 + 128 + h * 32];
    float s = 0.0f;
#pragma unroll
    for (int i = 0; i < 8; i++) {
      float4 v = *(const float4*)(kp + i * 4);
      s = fmaf(v.x, v.x, s);
      s = fmaf(v.y, v.y, s);
      s = fmaf(v.z, v.z, s);
      s = fmaf(v.w, v.w, s);
    }
    best = fmaxf(best, s);
  }
#pragma unroll
  for (int off = 32; off >= 1; off >>= 1)
    best = fmaxf(best, __shfl_xor(best, off, 64));
  __shared__ float red[4];
  int wave = threadIdx.x >> 6;
  if ((threadIdx.x & 63) == 0) red[wave] = best;
  __syncthreads();
  if (threadIdx.x == 0) {
    float m = fmaxf(fmaxf(red[0], red[1]), fmaxf(red[2], red[3]));
    kmax2[blockIdx.x] = m;
  }
}

// ---------------- attention via MFMA (flash-style, single pass, C-S bound) --------------
// grid: 128 g x 4 h x 2 halves = 1024 blocks; block 256 thr / 4 waves.
// Wave w owns 64 queries qb = half*256 + w*64. Loop 16 chunks of 32 keys:
//   S = Q'.K^T via 4 split-MFMAs (Q' = Q*scale*log2e); P = exp2(S - M) with
//   M = |q'|*|k|max (Cauchy-Schwarz, softmax shift-invariant); P split hi/lo ->
//   per-wave LDS -> A-frags; O += 3 split-MFMAs with V^T (+ ones col -> l).
// Fragment conventions identical to gemm_mfma/wprep (verified R5/R6):
//   A: lane=A[m=lane&15][k=quad*8+j]; B: lane=B[k=quad*8+j][n=lane&15];
//   C/D: col=lane&15, row=quad*4+reg.
__global__ __launch_bounds__(256, 2) void attn_mfma_kernel(
    const float* __restrict__ qkv, const float* __restrict__ kmax2,
    unsigned short* __restrict__ ohi, unsigned short* __restrict__ olo) {
  int b = blockIdx.x;
  int g = b >> 3;
  int h = (b >> 1) & 3;
  int half = b & 1;
  int t = threadIdx.x;
  int wave = t >> 6;
  int lane = t & 63;
  int quad = lane >> 4;
  int l15 = lane & 15;
  size_t gbase = (size_t)g * NPG;
  int qb = half * 256 + wave * 64;

  const float cf = 0.17677669529663687f * 1.4426950408889634f;  // scale*log2(e)

  __shared__ unsigned short Kh[32][40], Kl[32][40];   // [key][dim], 80B rows (16B-aligned)
  __shared__ unsigned short Vh[33][40], Vl[33][40];   // [dim][key] transposed; Vh row 32=ones
  __shared__ char wbuf[4][10240] __attribute__((aligned(16)));  // per-wave P / O-transpose

  unsigned short* Ph = (unsigned short*)wbuf[wave];        // [64][40] bf16
  unsigned short* Pl = Ph + 64 * 40;                       // [64][40] bf16
  float* Ot = (float*)wbuf[wave];                          // [64][36] f32 (epilogue/qn)

  // ---- Q fragments (global loads, scaled by cf, split hi/lo) + |q'|^2 ----
  bf16x8 qh[4], ql[4];
  float qn2p[4];
#pragma unroll
  for (int mt = 0; mt < 4; mt++) {
    const float* qp = &qkv[(gbase + qb + mt * 16 + l15) * 384 + h * 32 + quad * 8];
    float4 f0 = *(const float4*)qp;
    float4 f1 = *(const float4*)(qp + 4);
    float v[8] = {f0.x * cf, f0.y * cf, f0.z * cf, f0.w * cf,
                  f1.x * cf, f1.y * cf, f1.z * cf, f1.w * cf};
    u16x8 hh, ll;
    float s = 0.0f;
#pragma unroll
    for (int j = 0; j < 8; j++) {
      unsigned short hi_, lo_;
      split_bf(v[j], hi_, lo_);
      hh[j] = hi_;
      ll[j] = lo_;
      s = fmaf(v[j], v[j], s);
    }
    qh[mt] = __builtin_bit_cast(bf16x8, hh);
    ql[mt] = __builtin_bit_cast(bf16x8, ll);
    s += __shfl_xor(s, 16);
    s += __shfl_xor(s, 32);
    qn2p[mt] = s;  // full |q'|^2 for query mt*16 + l15
  }
  // exchange |q'|^2 so each lane gets the bound for its C-layout rows
  if (quad == 0) {
#pragma unroll
    for (int mt = 0; mt < 4; mt++) Ot[mt * 16 + l15] = qn2p[mt];
  }
  float km2 = kmax2[g * 4 + h];
  float Mq[4][4];
#pragma unroll
  for (int mt = 0; mt < 4; mt++)
#pragma unroll
    for (int r = 0; r < 4; r++)
      Mq[mt][r] = sqrtf(Ot[mt * 16 + quad * 4 + r] * km2);

  f32x4 Oa[4][3];
#pragma unroll
  for (int mt = 0; mt < 4; mt++)
#pragma unroll
    for (int nt = 0; nt < 3; nt++) Oa[mt][nt] = (f32x4)0.0f;

  for (int c = 0; c < 16; c++) {
    __syncthreads();  // previous chunk's K/V reads complete
    // ---- stage K rows (threads 128-255): key=t2>>2, dims (t2&3)*8 ----
    if (t >= 128) {
      int t2 = t - 128;
      int key = t2 >> 2;
      int ds = (t2 & 3) * 8;
      const float* kp = &qkv[(gbase + (size_t)(c * 32 + key)) * 384 + 128 + h * 32 + ds];
      float4 f0 = *(const float4*)kp;
      float4 f1 = *(const float4*)(kp + 4);
      float v[8] = {f0.x, f0.y, f0.z, f0.w, f1.x, f1.y, f1.z, f1.w};
      u16x8 hh, ll;
#pragma unroll
      for (int j = 0; j < 8; j++) {
        unsigned short hi_, lo_;
        split_bf(v[j], hi_, lo_);
        hh[j] = hi_;
        ll[j] = lo_;
      }
      *(u16x8*)&Kh[key][ds] = hh;
      *(u16x8*)&Kl[key][ds] = ll;
    } else if (t < 64) {
      // ---- stage V^T 4x4 blocks (threads 0-63) ----
      int keyb = (t & 7) * 4;
      int dvb = (t >> 3) * 4;
      float4 r0 = *(const float4*)&qkv[(gbase + (size_t)(c * 32 + keyb + 0)) * 384 + 256 + h * 32 + dvb];
      float4 r1 = *(const float4*)&qkv[(gbase + (size_t)(c * 32 + keyb + 1)) * 384 + 256 + h * 32 + dvb];
      float4 r2 = *(const float4*)&qkv[(gbase + (size_t)(c * 32 + keyb + 2)) * 384 + 256 + h * 32 + dvb];
      float4 r3 = *(const float4*)&qkv[(gbase + (size_t)(c * 32 + keyb + 3)) * 384 + 256 + h * 32 + dvb];
      float rr[4][4] = {{r0.x, r0.y, r0.z, r0.w}, {r1.x, r1.y, r1.z, r1.w},
                        {r2.x, r2.y, r2.z, r2.w}, {r3.x, r3.y, r3.z, r3.w}};
#pragma unroll
      for (int c2 = 0; c2 < 4; c2++) {
        ushort4 hv, lv;
        unsigned short hi_, lo_;
        split_bf(rr[0][c2], hi_, lo_); hv.x = hi_; lv.x = lo_;
        split_bf(rr[1][c2], hi_, lo_); hv.y = hi_; lv.y = lo_;
        split_bf(rr[2][c2], hi_, lo_); hv.z = hi_; lv.z = lo_;
        split_bf(rr[3][c2], hi_, lo_); hv.w = hi_; lv.w = lo_;
        *(ushort4*)&Vh[dvb + c2][keyb] = hv;
        *(ushort4*)&Vl[dvb + c2][keyb] = lv;
      }
    } else if (t < 68) {
      // ones row for l-column (dv=32)
      int i = t - 64;
      u16x8 ones;
#pragma unroll
      for (int j = 0; j < 8; j++) ones[j] = 0x3F80;
      *(u16x8*)&Vh[32][i * 8] = ones;
    }
    __syncthreads();

    // ---- QK^T -> S -> P (exp2, split, store to per-wave LDS) ----
#pragma unroll
    for (int nt = 0; nt < 2; nt++) {
      bf16x8 bkh = *(const bf16x8*)&Kh[nt * 16 + l15][quad * 8];
      bf16x8 bkl = *(const bf16x8*)&Kl[nt * 16 + l15][quad * 8];
#pragma unroll
      for (int mt = 0; mt < 4; mt++) {
        f32x4 S = (f32x4)0.0f;
        S = __builtin_amdgcn_mfma_f32_16x16x32_bf16(qh[mt], bkh, S, 0, 0, 0);
        S = __builtin_amdgcn_mfma_f32_16x16x32_bf16(qh[mt], bkl, S, 0, 0, 0);
        S = __builtin_amdgcn_mfma_f32_16x16x32_bf16(ql[mt], bkh, S, 0, 0, 0);
        S = __builtin_amdgcn_mfma_f32_16x16x32_bf16(ql[mt], bkl, S, 0, 0, 0);
#pragma unroll
        for (int r = 0; r < 4; r++) {
          float p = __builtin_exp2f(S[r] - Mq[mt][r]);
          unsigned short hi_, lo_;
          split_bf(p, hi_, lo_);
          int row = mt * 16 + quad * 4 + r;
          Ph[row * 40 + nt * 16 + l15] = hi_;
          Pl[row * 40 + nt * 16 + l15] = lo_;
        }
      }
    }
    // ---- PV: P A-frags x V^T B-frags ----
    bf16x8 pah[4], pal[4];
#pragma unroll
    for (int mt = 0; mt < 4; mt++) {
      pah[mt] = *(const bf16x8*)&Ph[(mt * 16 + l15) * 40 + quad * 8];
      pal[mt] = *(const bf16x8*)&Pl[(mt * 16 + l15) * 40 + quad * 8];
    }
#pragma unroll
    for (int nt = 0; nt < 3; nt++) {
      bf16x8 bvh = *(const bf16x8*)&Vh[nt * 16 + l15][quad * 8];
      if (nt < 2) {
        bf16x8 bvl = *(const bf16x8*)&Vl[nt * 16 + l15][quad * 8];
#pragma unroll
        for (int mt = 0; mt < 4; mt++) {
          Oa[mt][nt] = __builtin_amdgcn_mfma_f32_16x16x32_bf16(pah[mt], bvh, Oa[mt][nt], 0, 0, 0);
          Oa[mt][nt] = __builtin_amdgcn_mfma_f32_16x16x32_bf16(pah[mt], bvl, Oa[mt][nt], 0, 0, 0);
          Oa[mt][nt] = __builtin_amdgcn_mfma_f32_16x16x32_bf16(pal[mt], bvh, Oa[mt][nt], 0, 0, 0);
        }
      } else {
#pragma unroll
        for (int mt = 0; mt < 4; mt++) {
          Oa[mt][nt] = __builtin_amdgcn_mfma_f32_16x16x32_bf16(pah[mt], bvh, Oa[mt][nt], 0, 0, 0);
          Oa[mt][nt] = __builtin_amdgcn_mfma_f32_16x16x32_bf16(pal[mt], bvh, Oa[mt][nt], 0, 0, 0);
        }
      }
    }
  }

  // ---- epilogue: transpose O through per-wave LDS, normalize, split-bf16 store ----
  // (per-wave buffer; wave-lockstep ds ordering makes this barrier-free)
#pragma unroll
  for (int mt = 0; mt < 4; mt++) {
#pragma unroll
    for (int r = 0; r < 4; r++) {
      int row = mt * 16 + quad * 4 + r;
      Ot[row * 36 + l15] = Oa[mt][0][r];
      Ot[row * 36 + 16 + l15] = Oa[mt][1][r];
      if (l15 == 0) Ot[row * 36 + 32] = Oa[mt][2][r];  // l = ones-column
    }
  }
  {
    int row = lane;  // wave's query row
    float inv = 1.0f / Ot[row * 36 + 32];
    size_t node = gbase + qb + row;
    u16x8 vh, vl;
#pragma unroll
    for (int seg = 0; seg < 4; seg++) {
#pragma unroll
      for (int j = 0; j < 8; j++) {
        unsigned short hi_, lo_;
        split_bf(Ot[row * 36 + seg * 8 + j] * inv, hi_, lo_);
        vh[j] = hi_;
        vl[j] = lo_;
      }
      *(u16x8*)(ohi + node * 128 + h * 32 + seg * 8) = vh;
      *(u16x8*)(olo + node * 128 + h * 32 + seg * 8) = vl;
    }
  }
}

// ---------------- mean pool ----------------
__global__ __launch_bounds__(128) void pool_kernel(const float* __restrict__ fin,
                                                   float* __restrict__ emb) {
  int g = blockIdx.x, c = threadIdx.x;
  const float* p = fin + (size_t)g * NPG * HID + c;
  float s = 0.0f;
  for (int i = 0; i < NPG; i++) s += p[(size_t)i * HID];
  emb[g * HID + c] = s * (1.0f / NPG);
}

extern "C" void kernel_launch(void* const* d_in, const int* in_sizes, int n_in,
                              void* d_out, int out_size, void* d_ws, size_t ws_size,
                              hipStream_t stream) {
  (void)in_sizes; (void)n_in; (void)out_size; (void)ws_size;
  const float* x          = (const float*)d_in[0];
  const float* W0         = (const float*)d_in[1];
  const float* b0         = (const float*)d_in[2];
  const float* Wh         = (const float*)d_in[3];
  const float* bh         = (const float*)d_in[4];
  const float* bn_gamma   = (const float*)d_in[5];
  const float* bn_beta    = (const float*)d_in[6];
  const float* bn_mean    = (const float*)d_in[7];
  const float* bn_var     = (const float*)d_in[8];
  const float* attn_in_w  = (const float*)d_in[9];
  const float* attn_in_b  = (const float*)d_in[10];
  const float* attn_out_w = (const float*)d_in[11];
  const float* attn_out_b = (const float*)d_in[12];
  const int* edge_index   = (const int*)d_in[13];
  const int* src = edge_index;
  const int* dst = edge_index + N_EDGES;

  char* ws = (char*)d_ws;
  size_t off = 0;
  auto alloc = [&](size_t bytes) -> void* {
    void* p = ws + off;
    off += (bytes + 255) & ~(size_t)255;
    return p;
  };
  int*   deg     = (int*)alloc((size_t)N_NODES * 4);
  int*   offsets = (int*)alloc((size_t)(N_NODES + 1) * 4);
  int*   cursor  = (int*)alloc((size_t)N_NODES * 4);
  int*   csr     = (int*)alloc((size_t)N_EDGES * 4);
  float* dis     = (float*)alloc((size_t)N_NODES * 4);
  float* bufA    = (float*)alloc((size_t)N_NODES * HID * 4);   // h fp32; later f_hi/f_lo
  unsigned short* zhi = (unsigned short*)alloc((size_t)N_NODES * HID * 2);  // also o_hi
  unsigned short* zlo = (unsigned short*)alloc((size_t)N_NODES * HID * 2);  // also o_lo
  float* qkvb    = (float*)alloc((size_t)N_NODES * 384 * 4);
  float* kmax2   = (float*)alloc((size_t)N_GRAPHS * 4 * 4);
  unsigned short* w0h = (unsigned short*)alloc(8192 * 2);
  unsigned short* w0l = (unsigned short*)alloc(8192 * 2);
  unsigned short* whh[3], *whl[3];
  for (int i = 0; i < 3; i++) {
    whh[i] = (unsigned short*)alloc(16384 * 2);
    whl[i] = (unsigned short*)alloc(16384 * 2);
  }
  unsigned short* wqh = (unsigned short*)alloc(49152 * 2);
  unsigned short* wql = (unsigned short*)alloc(49152 * 2);
  unsigned short* woh = (unsigned short*)alloc(16384 * 2);
  unsigned short* wol = (unsigned short*)alloc(16384 * 2);

  unsigned short* fhi = (unsigned short*)bufA;
  unsigned short* flo = fhi + (size_t)N_NODES * HID;

  float* fin = (float*)d_out;                       // [N, HID]
  float* emb = fin + (size_t)N_NODES * HID;         // [G, HID]

  hipMemsetAsync(deg, 0, (size_t)N_NODES * 4, stream);
  hist_kernel<<<N_EDGES / 256, 256, 0, stream>>>(dst, deg);
  dis_kernel<<<N_NODES / 256, 256, 0, stream>>>(deg, dis);
  scan_kernel<<<1, 1024, 0, stream>>>(deg, offsets, cursor);
  fill_kernel<<<N_EDGES / 256, 256, 0, stream>>>(src, dst, cursor, csr);

  wprep_kernel<false><<<4, 256, 0, stream>>>(W0, 64, 128, w0h, w0l);
  for (int i = 0; i < 3; i++)
    wprep_kernel<false><<<8, 256, 0, stream>>>(Wh + (size_t)i * HID * HID, 128, 128,
                                               whh[i], whl[i]);
  wprep_kernel<true><<<24, 256, 0, stream>>>(attn_in_w, 128, 384, wqh, wql);
  wprep_kernel<true><<<8, 256, 0, stream>>>(attn_out_w, 128, 128, woh, wol);

  dim3 ggrid(N_NODES / 128, 1);
  agg64_kernel<<<N_NODES / 4, 256, 0, stream>>>(x, dis, offsets, csr, zhi, zlo);
  gemm_mfma<64, 128, true, true, false><<<ggrid, 256, 0, stream>>>(
      zhi, zlo, w0h, w0l, b0, bn_gamma, bn_beta, bn_mean, bn_var, bufA, nullptr, nullptr);
  for (int L = 0; L < 2; L++) {
    agg128_kernel<<<N_NODES / 4, 256, 0, stream>>>(bufA, dis, offsets, csr, zhi, zlo);
    gemm_mfma<128, 128, true, true, false><<<ggrid, 256, 0, stream>>>(
        zhi, zlo, whh[L], whl[L], bh + (size_t)L * HID,
        bn_gamma + (size_t)(L + 1) * HID, bn_beta + (size_t)(L + 1) * HID,
        bn_mean + (size_t)(L + 1) * HID, bn_var + (size_t)(L + 1) * HID,
        bufA, nullptr, nullptr);
  }
  agg128_kernel<<<N_NODES / 4, 256, 0, stream>>>(bufA, dis, offsets, csr, zhi, zlo);
  gemm_mfma<128, 128, true, true, true><<<ggrid, 256, 0, stream>>>(
      zhi, zlo, whh[2], whl[2], bh + (size_t)2 * HID,
      bn_gamma + (size_t)3 * HID, bn_beta + (size_t)3 * HID,
      bn_mean + (size_t)3 * HID, bn_var + (size_t)3 * HID,
      nullptr, fhi, flo);
  dim3 qgrid(N_NODES / 128, 3);
  gemm_mfma<128, 384, false, false, false><<<qgrid, 256, 0, stream>>>(
      fhi, flo, wqh, wql, attn_in_b, nullptr, nullptr, nullptr, nullptr,
      qkvb, nullptr, nullptr);
  knorm_kernel<<<N_GRAPHS * 4, 256, 0, stream>>>(qkvb, kmax2);
  attn_mfma_kernel<<<N_GRAPHS * 4 * 2, 256, 0, stream>>>(qkvb, kmax2, zhi, zlo);
  gemm_mfma<128, 128, false, false, false><<<ggrid, 256, 0, stream>>>(
      zhi, zlo, woh, wol, attn_out_b, nullptr, nullptr, nullptr, nullptr,
      fin, nullptr, nullptr);
  pool_kernel<<<N_GRAPHS, 128, 0, stream>>>(fin, emb);
}